// Round 16
// baseline (329.791 us; speedup 1.0000x reference)
//
#include <hip/hip_runtime.h>
#include <stdint.h>
#include <math.h>

typedef uint16_t u16; typedef uint32_t u32;
typedef __bf16 bf16x8 __attribute__((ext_vector_type(8)));
typedef float  f32x4  __attribute__((ext_vector_type(4)));
typedef u32 __attribute__((address_space(1))) gu32;
typedef u32 __attribute__((address_space(3))) lu32;

// ---- ws layout ----
#define FOFF_FUP    0        // 12 floats (up==down filter)
#define FOFF_KG     16       // 4
#define FOFF_GAUSS  24       // 9
#define FOFF_PART   40       // 8 per-batch styles^2 partial sums
#define FOFF_H3     48       // 36*64
#define FOFF_STYLES 2368     // 8*512
#define FOFF_KK     6464     // 9*512  (tap-major)
#define OFFB_WB  ((size_t)65536)          // 8*512*512 bf16 = 4MB (ends 4259840)
// filter matrices (bf16) in the gap 4259840..8388608:
#define OFFB_MUV ((size_t)4456448)        // Uv[48][32]  = 3072 B
#define OFFB_MUH ((size_t)4459520)        // Uh[144][96] = 27648 B
#define OFFB_MDV ((size_t)4487168)        // Dv[16][64]  = 2048 B
#define OFFB_MDH ((size_t)4489216)        // Dh[64][160] = 20480 B (ends 4509696)
#define OFFB_XT  ((size_t)(8u<<20))       // 8*4096*512 bf16 = 32MB ; aliased by y2
#define OFFB_Y1  ((size_t)(45u<<20))      // 8*4480*512 bf16 = 35MB

static __device__ __forceinline__ u16 f2b(float f) {
  union { float f; u32 u; } v; v.f = f;
  u32 u = v.u;
  return (u16)((u + 0x7fffu + ((u >> 16) & 1u)) >> 16);
}
static __device__ __forceinline__ float b2f(u16 h) {
  union { u32 u; float f; } v; v.u = ((u32)h) << 16; return v.f;
}

// ---------- device double-precision filter construction ----------
static __device__ double bessel_i0(double x) {
  double t = x * 0.5, t2 = t * t;
  double term = 1.0, sum = 1.0;
  for (int k = 1; k < 40; k++) {
    term *= t2 / ((double)k * (double)k);
    sum += term;
    if (term < 1e-17 * sum) break;
  }
  return sum;
}
static __device__ void firwin_dev(int numtaps, double cutoff, double width, double fs, float* out) {
  double nyq = fs * 0.5;
  double atten = 2.285 * (numtaps - 1) * 3.14159265358979323846 * (width / nyq) + 7.95;
  double beta;
  if (atten > 50.0) beta = 0.1102 * (atten - 8.7);
  else if (atten > 21.0) beta = 0.5842 * pow(atten - 21.0, 0.4) + 0.07886 * (atten - 21.0);
  else beta = 0.0;
  double c = cutoff / nyq;
  double i0b = bessel_i0(beta);
  double h[16]; double s = 0.0;
  for (int n = 0; n < numtaps; n++) {
    double m = n - (numtaps - 1) * 0.5;
    double x = c * m;
    double pix = 3.14159265358979323846 * x;
    double snc = (x == 0.0) ? 1.0 : sin(pix) / pix;
    double r = 2.0 * n / (double)(numtaps - 1) - 1.0;
    double arg = 1.0 - r * r; if (arg < 0.0) arg = 0.0;
    double kais = bessel_i0(beta * sqrt(arg)) / i0b;
    h[n] = c * snc * kais; s += h[n];
  }
  for (int n = 0; n < numtaps; n++) out[n] = (float)(h[n] / s);
}

// ---------- K1: filters + gauss + SIREN h3 + MFMA filter matrices ----------
__global__ void k_setup(const float* __restrict__ sw0, const float* __restrict__ sb0,
                        const float* __restrict__ sw1, const float* __restrict__ sb1,
                        const float* __restrict__ sw2, const float* __restrict__ sb2,
                        float* __restrict__ ws) {
  __shared__ float hA[2304], hB[2304];
  int t = threadIdx.x;
  if (t == 0) {
    firwin_dev(12, 32.0, 2.0 * 32.0 * (sqrt(2.0) - 1.0), 128.0, ws + FOFF_FUP);
  }
  if (t == 64) {
    double kc = 1.5;
    firwin_dev(4, kc, 2.0 * kc * (sqrt(2.0) - 1.0), kc * 2.0 * pow(2.0, 0.1), ws + FOFF_KG);
  }
  if (t == 128) {
    double s2 = 0.5;
    double gk[3];
    for (int k = 0; k < 3; k++) {
      double kn = k - 1;
      gk[k] = exp(-kn * kn / (2.0 * s2)) / sqrt(2.0 * 3.14159265358979323846 * s2);
    }
    for (int i = 0; i < 3; i++)
      for (int j = 0; j < 3; j++)
        ws[FOFF_GAUSS + i * 3 + j] = (float)(sqrt(gk[i] * gk[j]) * 2.0);
  }
  if (t >= 192 && t < 200) ws[FOFF_PART + t - 192] = 0.f;
  for (int idx = t; idx < 2304; idx += 256) {
    int p = idx >> 6, u = idx & 63;
    float gx = (float)((2.0 * (p % 6) + 1.0) / 6.0 - 1.0);
    float gy = (float)((2.0 * (p / 6) + 1.0) / 6.0 - 1.0);
    hA[idx] = sinf(30.f * (gx * sw0[u] + gy * sw0[64 + u] + sb0[u]));
  }
  __syncthreads();   // fu now visible to all threads
  // build banded filter matrices (bf16, zero-padded)
  {
    float fuv[12];
    #pragma unroll
    for (int i = 0; i < 12; i++) fuv[i] = ws[FOFF_FUP + i];
    char* wsb = (char*)ws;
    u16* muv = (u16*)(wsb + OFFB_MUV);
    u16* muh = (u16*)(wsb + OFFB_MUH);
    u16* mdv = (u16*)(wsb + OFFB_MDV);
    u16* mdh = (u16*)(wsb + OFFB_MDH);
    for (int i = t; i < 48 * 32; i += 256) {       // Uv[r][s]
      int r = i >> 5, s = i & 31;
      float v = 0.f;
      if (r < 42 && s < 26) {
        int d = (r >> 1) + 5 - s;
        if (d >= 0 && d <= 5) v = fuv[2 * d + (r & 1)];
      }
      muv[i] = f2b(v);
    }
    for (int i = t; i < 144 * 96; i += 256) {      // Uh[n][j]
      int n = i / 96, j = i - n * 96;
      float v = 0.f;
      if (n < 138 && j < 66) {
        int k = (n >> 1) + 1 - j;
        if (k >= 0 && k <= 5) v = fuv[2 * k + (n & 1)];
      }
      muh[i] = f2b(v);
    }
    for (int i = t; i < 16 * 64; i += 256) {       // Dv[R][ar]
      int R = i >> 6, ar = i & 63;
      float v = 0.f;
      if (ar < 42) {
        int q = ar - 2 * R;
        if (q >= 0 && q <= 11) v = fuv[11 - q];
      }
      mdv[i] = f2b(v);
    }
    for (int i = t; i < 64 * 160; i += 256) {      // Dh[ox][ac]
      int ox = i / 160, ac = i - ox * 160;
      float v = 0.f;
      if (ac < 138) {
        int q = ac - 2 * ox;
        if (q >= 0 && q <= 11) v = fuv[11 - q];
      }
      mdh[i] = f2b(v);
    }
  }
  for (int idx = t; idx < 2304; idx += 256) {
    int p = idx >> 6, u = idx & 63;
    float acc = sb1[u];
    for (int v = 0; v < 64; v++) acc += hA[p * 64 + v] * sw1[v * 64 + u];
    hB[idx] = sinf(acc);
  }
  __syncthreads();
  for (int idx = t; idx < 2304; idx += 256) {
    int p = idx >> 6, u = idx & 63;
    float acc = sb2[u];
    for (int v = 0; v < 64; v++) acc += hB[p * 64 + v] * sw2[v * 64 + u];
    ws[FOFF_H3 + idx] = sinf(acc);
  }
}

// ---------- K2: styles ----------
__global__ void k_styles(const float* __restrict__ w, const float* __restrict__ aw,
                         const float* __restrict__ ab, float* __restrict__ ws) {
  int b = blockIdx.y, j0 = blockIdx.x * 64, t = threadIdx.x;
  __shared__ float wl[512];
  __shared__ float red[256];
  wl[t] = w[b * 512 + t]; wl[t + 256] = w[b * 512 + 256 + t];
  __syncthreads();
  int j = j0 + (t & 63), kq = t >> 6;
  const f32x4* ar = (const f32x4*)(aw + (size_t)j * 512 + kq * 128);
  const f32x4* wv = (const f32x4*)(wl + kq * 128);
  float acc = 0.f;
  for (int k = 0; k < 32; k++) {
    f32x4 a = ar[k], c = wv[k];
    acc += a[0] * c[0] + a[1] * c[1] + a[2] * c[2] + a[3] * c[3];
  }
  red[t] = acc; __syncthreads();
  if (t < 64) {
    float sv = (red[t] + red[t + 64] + red[t + 128] + red[t + 192]) * 0.04419417382415922f + ab[j0 + t];
    ws[FOFF_STYLES + b * 512 + j0 + t] = sv;
    float p = sv * sv;
    for (int m = 32; m; m >>= 1) p += __shfl_xor(p, m);
    if (t == 0) atomicAdd(&ws[FOFF_PART + b], p);
  }
}

// ---------- K3: depthwise kernel construction ----------
__global__ void k_kw(const float* __restrict__ w3, const float* __restrict__ b3,
                     const float* __restrict__ kscale, const float* __restrict__ emap,
                     float* __restrict__ ws) {
  int t = threadIdx.x; int c0 = blockIdx.x * 64;
  __shared__ float h3l[2304];
  __shared__ float kw6[64][37];
  for (int i = t; i < 2304; i += 256) h3l[i] = ws[FOFF_H3 + i];
  __syncthreads();
  int cl = t & 63, pg = t >> 6;
  int c = c0 + cl;
  float acc[9];
  #pragma unroll
  for (int q = 0; q < 9; q++) acc[q] = b3[c];
  for (int v = 0; v < 64; v++) {
    float wv = w3[v * 512 + c];
    #pragma unroll
    for (int q = 0; q < 9; q++) acc[q] += h3l[(pg * 9 + q) * 64 + v] * wv;
  }
  float sc = 2.f / (1.f + expf(-kscale[c] * 0.1f));
  #pragma unroll
  for (int q = 0; q < 9; q++) kw6[cl][pg * 9 + q] = acc[q] * sc;
  __syncthreads();
  if (t < 64) {
    float kg[4];
    #pragma unroll
    for (int i = 0; i < 4; i++) kg[i] = ws[FOFF_KG + i];
    float pre[9];
    for (int u = 0; u < 3; u++)
      for (int vv = 0; vv < 3; vv++) {
        float s = 0.f;
        for (int t1 = 0; t1 < 4; t1++) {
          int a = 2 * u + t1 - 1;
          if (a < 0 || a > 5) continue;
          for (int t2 = 0; t2 < 4; t2++) {
            int bb = 2 * vv + t2 - 1;
            if (bb < 0 || bb > 5) continue;
            s += kg[3 - t1] * kg[3 - t2] * kw6[t][a * 6 + bb];
          }
        }
        pre[u * 3 + vv] = s;
      }
    float m = 0.f;
    #pragma unroll
    for (int q = 0; q < 9; q++) m += pre[q];
    m *= (1.f / 9.f);
    float ms = 0.f;
    #pragma unroll
    for (int q = 0; q < 9; q++) { pre[q] -= m; ms += pre[q] * pre[q]; }
    ms *= (1.f / 9.f);
    float r = 1.f / sqrtf(ms);
    float re = 1.f / sqrtf(emap[0]);
    #pragma unroll
    for (int q = 0; q < 9; q++)
      ws[FOFF_KK + q * 512 + (c0 + t)] = pre[q] * r * ws[FOFF_GAUSS + q] * re;
  }
}

// ---------- K4 v2: modulated weights, 4 waves/block (one o per wave) ----------
__global__ void k_wb(const float* __restrict__ sw, const float* __restrict__ ws,
                     u16* __restrict__ wb) {
  int wv = threadIdx.x >> 6, lane = threadIdx.x & 63;
  int o = blockIdx.x * 4 + wv, b = blockIdx.y;
  float ssum = 0.f;
  #pragma unroll
  for (int i = 0; i < 8; i++) ssum += ws[FOFF_PART + i];
  float rsn = 1.f / sqrtf(ssum * (1.f / 4096.f));
  float swv[8], stv[8];
  float s2 = 0.f;
  #pragma unroll
  for (int q = 0; q < 8; q++) {
    int i = lane + q * 64;
    swv[q] = sw[(size_t)o * 512 + i];
    stv[q] = ws[FOFF_STYLES + b * 512 + i];
    s2 += swv[q] * swv[q];
  }
  for (int m = 32; m; m >>= 1) s2 += __shfl_xor(s2, m);
  float r1 = 1.f / sqrtf(s2 * (1.f / 512.f));
  float tv[8]; float t2 = 0.f;
  #pragma unroll
  for (int q = 0; q < 8; q++) { tv[q] = swv[q] * r1 * stv[q] * rsn; t2 += tv[q] * tv[q]; }
  for (int m = 32; m; m >>= 1) t2 += __shfl_xor(t2, m);
  float r2 = 1.f / sqrtf(t2 + 1e-8f);
  #pragma unroll
  for (int q = 0; q < 8; q++)
    wb[((size_t)b * 512 + o) * 512 + lane + q * 64] = f2b(tv[q] * r2);
}

// ---------- K5: transpose+cast ----------
__global__ void k_transpose(const float* __restrict__ x, u16* __restrict__ xT) {
  int h = blockIdx.x, c0 = blockIdx.y * 64, b = blockIdx.z;
  int t = threadIdx.x;
  __shared__ u16 tl[64][66];
  int wcol = t & 63, cbase = t >> 6;
  const float* xp = x + ((size_t)(b * 512 + c0)) * 4096 + h * 64;
  #pragma unroll
  for (int k = 0; k < 16; k++) {
    int ci = cbase + k * 4;
    tl[ci][wcol] = f2b(xp[(size_t)ci * 4096 + wcol]);
  }
  __syncthreads();
  int cp = t & 31, wbse = t >> 5;
  u32* dst = (u32*)(xT + ((size_t)b * 4096 + h * 64) * 512 + c0);
  #pragma unroll
  for (int k = 0; k < 8; k++) {
    int w_ = wbse + k * 8;
    u32 v0 = tl[cp * 2][w_], v1 = tl[cp * 2 + 1][w_];
    dst[w_ * 256 + cp] = v0 | (v1 << 16);
  }
}

// ---------- K6: depthwise 3x3, registers-only ----------
__global__ void k_dw(const u16* __restrict__ xT, const float* __restrict__ ws,
                     u16* __restrict__ y1) {
  int tile = blockIdx.x, b = blockIdx.y, t = threadIdx.x;
  int c2 = t * 2;
  float2 kk[9];
  #pragma unroll
  for (int q = 0; q < 9; q++) kk[q] = *(const float2*)&ws[FOFF_KK + q * 512 + c2];
  #pragma unroll 2
  for (int pos = 0; pos < 16; pos++) {
    int hw = tile * 16 + pos;
    if (hw < 4356) {
      int h = hw / 66, w_ = hw - h * 66;
      float a0 = 0.f, a1 = 0.f;
      for (int i = 0; i < 3; i++) {
        int ih = h - 2 + i; if (ih < 0 || ih >= 64) continue;
        for (int j = 0; j < 3; j++) {
          int iw = w_ - 2 + j; if (iw < 0 || iw >= 64) continue;
          u32 xv = *(const u32*)(xT + ((size_t)b * 4096 + ih * 64 + iw) * 512 + c2);
          float2 kv = kk[i * 3 + j];
          a0 += kv.x * b2f((u16)xv);
          a1 += kv.y * b2f((u16)(xv >> 16));
        }
      }
      ((u32*)y1)[(((size_t)b * 4480 + hw) * 512 + c2) >> 1] = (u32)f2b(a0) | ((u32)f2b(a1) << 16);
    } else {
      ((u32*)y1)[(((size_t)b * 4480 + hw) * 512 + c2) >> 1] = 0u;
    }
  }
}

// ---------- K7: batched GEMM, XCD-aware remap ----------
__launch_bounds__(256, 4)
__global__ void k_gemm(const u16* __restrict__ wbm, const u16* __restrict__ y1,
                       const float* __restrict__ bias, u16* __restrict__ y2) {
  int lid = blockIdx.x + 35 * (blockIdx.y + (blockIdx.z << 2));
  int b  = lid & 7;
  int s_ = lid >> 3;
  int mt = s_ & 3;
  int nt = s_ >> 2;
  int t = threadIdx.x, lane = t & 63, wv = t >> 6;
  int wm = wv >> 1, wn = wv & 1;
  __shared__ u16 Al[4096];
  __shared__ u16 Bl[4096];
  f32x4 acc[4][4];
  #pragma unroll
  for (int i = 0; i < 4; i++)
    #pragma unroll
    for (int j = 0; j < 4; j++)
      acc[i][j] = (f32x4){0.f, 0.f, 0.f, 0.f};

  const size_t Abase = (size_t)b * 512 + mt * 128;
  const size_t Bbase = (size_t)b * 4480 + nt * 128;
  int lrow = lane >> 2, dch = lane & 3;
  int cp = lane >> 4;

  for (int ks = 0; ks < 16; ks++) {
    int k0 = ks * 32;
    __syncthreads();
    #pragma unroll
    for (int half = 0; half < 2; half++) {
      int rbase = half * 64 + wv * 16;
      int row = rbase + lrow;
      int gch = dch ^ ((row >> 1) & 3);
      const u16* ga = wbm + (Abase + row) * 512 + k0 + gch * 8;
      const u16* gb = y1 + (Bbase + row) * 512 + k0 + gch * 8;
      __builtin_amdgcn_global_load_lds((const gu32*)ga, (lu32*)&Al[rbase * 32], 16, 0, 0);
      __builtin_amdgcn_global_load_lds((const gu32*)gb, (lu32*)&Bl[rbase * 32], 16, 0, 0);
    }
    asm volatile("s_waitcnt vmcnt(0)" ::: "memory");
    __syncthreads();
    bf16x8 af[4], bfr[4];
    #pragma unroll
    for (int mi = 0; mi < 4; mi++) {
      int row = wm * 64 + mi * 16 + (lane & 15);
      af[mi] = *(const bf16x8*)&Al[row * 32 + ((cp ^ ((row >> 1) & 3)) * 8)];
    }
    #pragma unroll
    for (int ni = 0; ni < 4; ni++) {
      int row = wn * 64 + ni * 16 + (lane & 15);
      bfr[ni] = *(const bf16x8*)&Bl[row * 32 + ((cp ^ ((row >> 1) & 3)) * 8)];
    }
    #pragma unroll
    for (int mi = 0; mi < 4; mi++)
      #pragma unroll
      for (int ni = 0; ni < 4; ni++)
        acc[mi][ni] = __builtin_amdgcn_mfma_f32_16x16x32_bf16(af[mi], bfr[ni], acc[mi][ni], 0, 0, 0);
  }
  int col0 = nt * 128 + wn * 64 + (lane & 15);
  int rb = (lane >> 4) * 4;
  #pragma unroll
  for (int mi = 0; mi < 4; mi++) {
    #pragma unroll
    for (int j = 0; j < 4; j++) {
      int o = mt * 128 + wm * 64 + mi * 16 + rb + j;
      float bv = bias[o];
      size_t rowoff = ((size_t)b * 512 + o) * 4480;
      #pragma unroll
      for (int ni = 0; ni < 4; ni++)
        y2[rowoff + col0 + ni * 16] = f2b(acc[mi][ni][j] + bv);
    }
  }
}

// ---------- K8 v12: v11 + complete region2 zero-cover (T1u cols 80..103) ----------
// Strides (u16): Yt 40, T1u 104, At 72, T3u 168.
// LDS 30720 B: region1 @0 (20736): Yt[80][40] -> At[144][72] ; region2 @20736 (9984): T1u[48][104] -> T3u[16][168]
// Every byte of region2 is initialized (S1 writes cols 0..79; phase-0 zeroes cols 80..103),
// so stale alias reads (T3u cols 144..159) are always finite -> 0 under mdh zero coeffs.
__launch_bounds__(256, 4)
__global__ void k_updown(const u16* __restrict__ y2,
                         const u16* __restrict__ muv, const u16* __restrict__ muh,
                         const u16* __restrict__ mdv, const u16* __restrict__ mdh,
                         float* __restrict__ out) {
  int g = blockIdx.x, o = blockIdx.y, b = blockIdx.z;
  int t = threadIdx.x, lane = t & 63, wv = t >> 6;
  int l15 = lane & 15, cp = lane >> 4, rb = cp * 4;
  __shared__ __align__(16) char smem[30720];
  u16* Yt  = (u16*)smem;             // [80][40]   (dead after S1)
  u16* At  = (u16*)smem;             // [144][72]  (aliases Yt; written in S2; pad cols 48..63 zeroed in S2)
  u16* T1u = (u16*)(smem + 20736);   // [48][104]  (dead after S2)
  u16* T3u = (u16*)(smem + 20736);   // [16][168]  (aliases T1u; stale reads finite by full cover)
  const int out_r0 = g * 16;
  const int yrow0 = out_r0 - 4;
  const u16* plane = y2 + ((size_t)b * 512 + o) * 4480;

  // ---- prefetch ALL coefficient fragments into registers (overlaps with staging below) ----
  bf16x8 cmuv[4];
  #pragma unroll
  for (int q = 0; q < 4; q++) {
    int tau = wv + 4 * q; int tc = (tau < 15) ? tau : 0;
    int mi = tc / 5;
    cmuv[q] = *(const bf16x8*)&muv[(mi * 16 + l15) * 32 + cp * 8];
  }
  bf16x8 cmuh[3][3];
  #pragma unroll
  for (int i = 0; i < 3; i++) {
    int ni = wv + 4 * i; int nc = (ni < 9) ? ni : 0;
    #pragma unroll
    for (int ks = 0; ks < 3; ks++)
      cmuh[i][ks] = *(const bf16x8*)&muh[(nc * 16 + l15) * 96 + ks * 32 + cp * 8];
  }
  bf16x8 cmdv0 = *(const bf16x8*)&mdv[l15 * 64 + cp * 8];
  bf16x8 cmdv1 = *(const bf16x8*)&mdv[l15 * 64 + 32 + cp * 8];
  bf16x8 cmdh[5];
  #pragma unroll
  for (int ks = 0; ks < 5; ks++)
    cmdh[ks] = *(const bf16x8*)&mdh[(wv * 16 + l15) * 160 + ks * 32 + cp * 8];

  // ---- phase 0: precise zero-set + Yt staging (disjoint addresses, one barrier) ----
  // zero Yt rows 0..65 cols 26..31 (beyond data, read by S1 cp=3)
  for (int idx = t; idx < 66 * 3; idx += 256) {
    int r = idx / 3, k = idx - r * 3;
    *(u32*)&Yt[r * 40 + 26 + 2 * k] = 0u;
  }
  // zero Yt rows 66..79 cols 0..31
  for (int idx = t; idx < 14 * 16; idx += 256) {
    int r = 66 + (idx >> 4), k = idx & 15;
    *(u32*)&Yt[r * 40 + 2 * k] = 0u;
  }
  // zero T1u rows 0..47 cols 80..103 (covers S2 ks=2 pad AND the stride pad aliased by T3u reads)
  for (int idx = t; idx < 48 * 12; idx += 256) {
    int r = idx / 12, k = idx - r * 12;
    *(u32*)&T1u[r * 104 + 80 + 2 * k] = 0u;
  }
  // stage Y transposed: Yt[j][s] = y[yrow0+s][j]  (rows 0..65, cols 0..25)
  for (int idx = t; idx < 26 * 66; idx += 256) {
    int s = idx / 66, j = idx - 66 * s;
    int grow = yrow0 + s;
    u16 v = 0;
    if (grow >= 0 && grow < 66) v = plane[(size_t)grow * 66 + j];
    Yt[j * 40 + s] = v;
  }
  __syncthreads();

  // S1: T1(48x80) = Uv(48x32) x Yt^T   (1 k-step)
  #pragma unroll
  for (int q = 0; q < 4; q++) {
    int tau = wv + 4 * q;
    if (tau < 15) {
      int mi = tau / 5, ni = tau - mi * 5;
      bf16x8 bfr = *(const bf16x8*)&Yt[(ni * 16 + l15) * 40 + cp * 8];
      f32x4 acc = (f32x4){0.f, 0.f, 0.f, 0.f};
      acc = __builtin_amdgcn_mfma_f32_16x16x32_bf16(cmuv[q], bfr, acc, 0, 0, 0);
      #pragma unroll
      for (int j = 0; j < 4; j++)
        T1u[(mi * 16 + rb + j) * 104 + ni * 16 + l15] = f2b(acc[j]);
    }
  }
  __syncthreads();

  // S2: T2(48x144) = T1(48x96) x Uh^T ; act ; store transposed At[c][r] + zero At pad cols 48..63
  #pragma unroll
  for (int i = 0; i < 3; i++) {
    int ni = wv + 4 * i;
    if (ni < 9) {
      #pragma unroll
      for (int mi = 0; mi < 3; mi++) {
        f32x4 acc = (f32x4){0.f, 0.f, 0.f, 0.f};
        #pragma unroll
        for (int ks = 0; ks < 3; ks++) {
          bf16x8 a = *(const bf16x8*)&T1u[(mi * 16 + l15) * 104 + ks * 32 + cp * 8];
          acc = __builtin_amdgcn_mfma_f32_16x16x32_bf16(a, cmuh[i][ks], acc, 0, 0, 0);
        }
        int c = ni * 16 + l15;
        u16 pv[4];
        #pragma unroll
        for (int j = 0; j < 4; j++) {
          float x = acc[j];
          x = fmaxf(x, 0.2f * x) * 5.65685424949238f;
          x = fminf(fmaxf(x, -256.f), 256.f);
          pv[j] = f2b(x);
        }
        u32 lo = (u32)pv[0] | ((u32)pv[1] << 16);
        u32 hi = (u32)pv[2] | ((u32)pv[3] << 16);
        *(uint2*)&At[c * 72 + mi * 16 + rb] = make_uint2(lo, hi);
      }
      // zero At pad cols 48..63 for this row (read by S3 k-step-1, mdv-masked but must be finite)
      *(uint2*)&At[(ni * 16 + l15) * 72 + 48 + rb] = make_uint2(0u, 0u);
    }
  }
  __syncthreads();

  // S3: T3(16x144) = Dv(16x64) x At^T   (2 k-steps)
  for (int ni = wv; ni < 9; ni += 4) {
    f32x4 acc = (f32x4){0.f, 0.f, 0.f, 0.f};
    bf16x8 b0 = *(const bf16x8*)&At[(ni * 16 + l15) * 72 + cp * 8];
    acc = __builtin_amdgcn_mfma_f32_16x16x32_bf16(cmdv0, b0, acc, 0, 0, 0);
    bf16x8 b1 = *(const bf16x8*)&At[(ni * 16 + l15) * 72 + 32 + cp * 8];
    acc = __builtin_amdgcn_mfma_f32_16x16x32_bf16(cmdv1, b1, acc, 0, 0, 0);
    #pragma unroll
    for (int j = 0; j < 4; j++)
      T3u[(rb + j) * 168 + ni * 16 + l15] = f2b(acc[j]);
  }
  __syncthreads();

  // S4: OUT(16x64) = T3(16x160) x Dh^T  (5 k-steps), wave ni = wv
  {
    f32x4 acc = (f32x4){0.f, 0.f, 0.f, 0.f};
    #pragma unroll
    for (int ks = 0; ks < 5; ks++) {
      bf16x8 a = *(const bf16x8*)&T3u[l15 * 168 + ks * 32 + cp * 8];
      acc = __builtin_amdgcn_mfma_f32_16x16x32_bf16(a, cmdh[ks], acc, 0, 0, 0);
    }
    float* op = out + (((size_t)b * 512 + o) * 64 + out_r0) * 64;
    #pragma unroll
    for (int j = 0; j < 4; j++)
      op[(rb + j) * 64 + wv * 16 + l15] = acc[j];
  }
}

extern "C" void kernel_launch(void* const* d_in, const int* in_sizes, int n_in,
                              void* d_out, int out_size, void* d_ws, size_t ws_size,
                              hipStream_t stream) {
  const float* x     = (const float*)d_in[0];
  const float* w     = (const float*)d_in[1];
  const float* aw    = (const float*)d_in[2];
  const float* ab    = (const float*)d_in[3];
  const float* swgt  = (const float*)d_in[4];
  const float* bias  = (const float*)d_in[5];
  const float* sw0   = (const float*)d_in[6];
  const float* sb0   = (const float*)d_in[7];
  const float* sw1   = (const float*)d_in[8];
  const float* sb1   = (const float*)d_in[9];
  const float* sw2   = (const float*)d_in[10];
  const float* sb2   = (const float*)d_in[11];
  const float* sw3   = (const float*)d_in[12];
  const float* sb3   = (const float*)d_in[13];
  const float* kscl  = (const float*)d_in[14];
  const float* ema   = (const float*)d_in[15];

  float* ws  = (float*)d_ws;
  char*  wsb = (char*)d_ws;
  u16* wbp = (u16*)(wsb + OFFB_WB);
  u16* xT  = (u16*)(wsb + OFFB_XT);
  u16* y2  = xT;
  u16* y1  = (u16*)(wsb + OFFB_Y1);
  u16* muv = (u16*)(wsb + OFFB_MUV);
  u16* muh = (u16*)(wsb + OFFB_MUH);
  u16* mdv = (u16*)(wsb + OFFB_MDV);
  u16* mdh = (u16*)(wsb + OFFB_MDH);

  k_setup<<<dim3(1), dim3(256), 0, stream>>>(sw0, sb0, sw1, sb1, sw2, sb2, ws);
  k_styles<<<dim3(8, 8), dim3(256), 0, stream>>>(w, aw, ab, ws);
  k_kw<<<dim3(8), dim3(256), 0, stream>>>(sw3, sb3, kscl, ema, ws);
  k_wb<<<dim3(128, 8), dim3(256), 0, stream>>>(swgt, ws, wbp);
  k_transpose<<<dim3(64, 8, 8), dim3(256), 0, stream>>>(x, xT);
  k_dw<<<dim3(280, 8), dim3(256), 0, stream>>>(xT, ws, y1);
  k_gemm<<<dim3(35, 4, 8), dim3(256), 0, stream>>>(wbp, y1, bias, y2);
  k_updown<<<dim3(4, 512, 8), dim3(256), 0, stream>>>(y2, muv, muh, mdv, mdh, (float*)d_out);
}

// Round 17
// 300.626 us; speedup vs baseline: 1.0970x; 1.0970x over previous
//
#include <hip/hip_runtime.h>
#include <stdint.h>
#include <math.h>

typedef uint16_t u16; typedef uint32_t u32;
typedef __bf16 bf16x8 __attribute__((ext_vector_type(8)));
typedef float  f32x4  __attribute__((ext_vector_type(4)));
typedef u32 __attribute__((address_space(1))) gu32;
typedef u32 __attribute__((address_space(3))) lu32;

// ---- ws layout ----
#define FOFF_FUP    0        // 12 floats (up==down filter)
#define FOFF_KG     16       // 4
#define FOFF_GAUSS  24       // 9
#define FOFF_PART   40       // 8 per-batch styles^2 partial sums
#define FOFF_H3     48       // 36*64
#define FOFF_STYLES 2368     // 8*512
#define FOFF_KK     6464     // 9*512  (tap-major)
#define OFFB_WB  ((size_t)65536)          // 8*512*512 bf16 = 4MB (ends 4259840)
#define OFFB_MUV ((size_t)4456448)        // Uv[48][32]  = 3072 B
#define OFFB_MUH ((size_t)4459520)        // Uh[144][96] = 27648 B
#define OFFB_MDV ((size_t)4487168)        // Dv[16][64]  = 2048 B
#define OFFB_MDH ((size_t)4489216)        // Dh[64][160] = 20480 B
#define OFFB_XT  ((size_t)(8u<<20))       // 8*4096*512 bf16 = 32MB ; aliased by y2
#define OFFB_Y1  ((size_t)(45u<<20))      // 8*4480*512 bf16 = 35MB

static __device__ __forceinline__ u16 f2b(float f) {
  union { float f; u32 u; } v; v.f = f;
  u32 u = v.u;
  return (u16)((u + 0x7fffu + ((u >> 16) & 1u)) >> 16);
}
static __device__ __forceinline__ float b2f(u16 h) {
  union { u32 u; float f; } v; v.u = ((u32)h) << 16; return v.f;
}

// ---------- float filter construction (pipeline is bf16; 1e-6 rel error is negligible) ----------
static __device__ float bessel_i0f(float x) {
  float t = x * 0.5f, t2 = t * t;
  float term = 1.f, sum = 1.f;
  for (int k = 1; k < 32; k++) {
    term *= t2 / ((float)k * (float)k);
    sum += term;
    if (term < 1e-8f * sum) break;
  }
  return sum;
}
static __device__ void firwin_devf(int numtaps, float cutoff, float width, float fs, float* out) {
  float nyq = fs * 0.5f;
  float atten = 2.285f * (numtaps - 1) * 3.14159265358979f * (width / nyq) + 7.95f;
  float beta;
  if (atten > 50.f) beta = 0.1102f * (atten - 8.7f);
  else if (atten > 21.f) beta = 0.5842f * powf(atten - 21.f, 0.4f) + 0.07886f * (atten - 21.f);
  else beta = 0.f;
  float c = cutoff / nyq;
  float i0b = bessel_i0f(beta);
  float h[16]; float s = 0.f;
  for (int n = 0; n < numtaps; n++) {
    float m = n - (numtaps - 1) * 0.5f;
    float x = c * m;
    float pix = 3.14159265358979f * x;
    float snc = (x == 0.f) ? 1.f : __sinf(pix) / pix;
    float r = 2.f * n / (float)(numtaps - 1) - 1.f;
    float arg = 1.f - r * r; if (arg < 0.f) arg = 0.f;
    float kais = bessel_i0f(beta * sqrtf(arg)) / i0b;
    h[n] = c * snc * kais; s += h[n];
  }
  for (int n = 0; n < numtaps; n++) out[n] = h[n] / s;
}

// ---------- K1: filters + gauss + SIREN h3 + MFMA filter matrices ----------
__global__ void k_setup(const float* __restrict__ sw0, const float* __restrict__ sb0,
                        const float* __restrict__ sw1, const float* __restrict__ sb1,
                        const float* __restrict__ sw2, const float* __restrict__ sb2,
                        float* __restrict__ ws) {
  __shared__ float hA[2304], hB[2304];
  int t = threadIdx.x;
  if (t == 0) {
    firwin_devf(12, 32.f, 2.f * 32.f * 0.41421356237309515f, 128.f, ws + FOFF_FUP);
  }
  if (t == 64) {
    float kc = 1.5f;
    firwin_devf(4, kc, 2.f * kc * 0.41421356237309515f, kc * 2.f * 1.0717734625362931f, ws + FOFF_KG);
  }
  if (t == 128) {
    float s2 = 0.5f;
    float gk[3];
    for (int k = 0; k < 3; k++) {
      float kn = (float)(k - 1);
      gk[k] = expf(-kn * kn / (2.f * s2)) / sqrtf(2.f * 3.14159265358979f * s2);
    }
    for (int i = 0; i < 3; i++)
      for (int j = 0; j < 3; j++)
        ws[FOFF_GAUSS + i * 3 + j] = sqrtf(gk[i] * gk[j]) * 2.f;
  }
  if (t >= 192 && t < 200) ws[FOFF_PART + t - 192] = 0.f;
  for (int idx = t; idx < 2304; idx += 256) {
    int p = idx >> 6, u = idx & 63;
    float gx = (2.f * (p % 6) + 1.f) / 6.f - 1.f;
    float gy = (2.f * (p / 6) + 1.f) / 6.f - 1.f;
    hA[idx] = sinf(30.f * (gx * sw0[u] + gy * sw0[64 + u] + sb0[u]));
  }
  __syncthreads();   // fu now visible to all threads
  {
    float fuv[12];
    #pragma unroll
    for (int i = 0; i < 12; i++) fuv[i] = ws[FOFF_FUP + i];
    char* wsb = (char*)ws;
    u16* muv = (u16*)(wsb + OFFB_MUV);
    u16* muh = (u16*)(wsb + OFFB_MUH);
    u16* mdv = (u16*)(wsb + OFFB_MDV);
    u16* mdh = (u16*)(wsb + OFFB_MDH);
    for (int i = t; i < 48 * 32; i += 256) {       // Uv[r][s]
      int r = i >> 5, s = i & 31;
      float v = 0.f;
      if (r < 42 && s < 26) {
        int d = (r >> 1) + 5 - s;
        if (d >= 0 && d <= 5) v = fuv[2 * d + (r & 1)];
      }
      muv[i] = f2b(v);
    }
    for (int i = t; i < 144 * 96; i += 256) {      // Uh[n][j]
      int n = i / 96, j = i - n * 96;
      float v = 0.f;
      if (n < 138 && j < 66) {
        int k = (n >> 1) + 1 - j;
        if (k >= 0 && k <= 5) v = fuv[2 * k + (n & 1)];
      }
      muh[i] = f2b(v);
    }
    for (int i = t; i < 16 * 64; i += 256) {       // Dv[R][ar]
      int R = i >> 6, ar = i & 63;
      float v = 0.f;
      if (ar < 42) {
        int q = ar - 2 * R;
        if (q >= 0 && q <= 11) v = fuv[11 - q];
      }
      mdv[i] = f2b(v);
    }
    for (int i = t; i < 64 * 160; i += 256) {      // Dh[ox][ac]
      int ox = i / 160, ac = i - ox * 160;
      float v = 0.f;
      if (ac < 138) {
        int q = ac - 2 * ox;
        if (q >= 0 && q <= 11) v = fuv[11 - q];
      }
      mdh[i] = f2b(v);
    }
  }
  for (int idx = t; idx < 2304; idx += 256) {
    int p = idx >> 6, u = idx & 63;
    float acc = sb1[u];
    for (int v = 0; v < 64; v++) acc += hA[p * 64 + v] * sw1[v * 64 + u];
    hB[idx] = sinf(acc);
  }
  __syncthreads();
  for (int idx = t; idx < 2304; idx += 256) {
    int p = idx >> 6, u = idx & 63;
    float acc = sb2[u];
    for (int v = 0; v < 64; v++) acc += hB[p * 64 + v] * sw2[v * 64 + u];
    ws[FOFF_H3 + idx] = sinf(acc);
  }
}

// ---------- K2+K3 merged: blocks 0..63 styles, 64..71 depthwise-kernel construction ----------
__global__ void k_stkw(const float* __restrict__ w, const float* __restrict__ aw,
                       const float* __restrict__ ab,
                       const float* __restrict__ w3, const float* __restrict__ b3,
                       const float* __restrict__ kscale, const float* __restrict__ emap,
                       float* __restrict__ ws) {
  __shared__ __align__(16) char sm[18944];
  int t = threadIdx.x;
  if (blockIdx.x < 64) {
    // ---- styles ----
    float* wl  = (float*)sm;          // [512]
    float* red = (float*)(sm + 2048); // [256]
    int b = blockIdx.x >> 3, j0 = (blockIdx.x & 7) * 64;
    wl[t] = w[b * 512 + t]; wl[t + 256] = w[b * 512 + 256 + t];
    __syncthreads();
    int j = j0 + (t & 63), kq = t >> 6;
    const f32x4* ar = (const f32x4*)(aw + (size_t)j * 512 + kq * 128);
    const f32x4* wv = (const f32x4*)(wl + kq * 128);
    float acc = 0.f;
    for (int k = 0; k < 32; k++) {
      f32x4 a = ar[k], c = wv[k];
      acc += a[0] * c[0] + a[1] * c[1] + a[2] * c[2] + a[3] * c[3];
    }
    red[t] = acc; __syncthreads();
    if (t < 64) {
      float sv = (red[t] + red[t + 64] + red[t + 128] + red[t + 192]) * 0.04419417382415922f + ab[j0 + t];
      ws[FOFF_STYLES + b * 512 + j0 + t] = sv;
      float p = sv * sv;
      for (int m = 32; m; m >>= 1) p += __shfl_xor(p, m);
      if (t == 0) atomicAdd(&ws[FOFF_PART + b], p);
    }
  } else {
    // ---- kw construction ----
    float* h3l = (float*)sm;            // [2304]
    float (*kw6)[37] = (float(*)[37])(sm + 9216);  // [64][37]
    int c0 = (blockIdx.x - 64) * 64;
    for (int i = t; i < 2304; i += 256) h3l[i] = ws[FOFF_H3 + i];
    __syncthreads();
    int cl = t & 63, pg = t >> 6;
    int c = c0 + cl;
    float acc[9];
    #pragma unroll
    for (int q = 0; q < 9; q++) acc[q] = b3[c];
    for (int v = 0; v < 64; v++) {
      float wv = w3[v * 512 + c];
      #pragma unroll
      for (int q = 0; q < 9; q++) acc[q] += h3l[(pg * 9 + q) * 64 + v] * wv;
    }
    float sc = 2.f / (1.f + expf(-kscale[c] * 0.1f));
    #pragma unroll
    for (int q = 0; q < 9; q++) kw6[cl][pg * 9 + q] = acc[q] * sc;
    __syncthreads();
    if (t < 64) {
      float kg[4];
      #pragma unroll
      for (int i = 0; i < 4; i++) kg[i] = ws[FOFF_KG + i];
      float pre[9];
      for (int u = 0; u < 3; u++)
        for (int vv = 0; vv < 3; vv++) {
          float s = 0.f;
          for (int t1 = 0; t1 < 4; t1++) {
            int a = 2 * u + t1 - 1;
            if (a < 0 || a > 5) continue;
            for (int t2 = 0; t2 < 4; t2++) {
              int bb = 2 * vv + t2 - 1;
              if (bb < 0 || bb > 5) continue;
              s += kg[3 - t1] * kg[3 - t2] * kw6[t][a * 6 + bb];
            }
          }
          pre[u * 3 + vv] = s;
        }
      float m = 0.f;
      #pragma unroll
      for (int q = 0; q < 9; q++) m += pre[q];
      m *= (1.f / 9.f);
      float ms = 0.f;
      #pragma unroll
      for (int q = 0; q < 9; q++) { pre[q] -= m; ms += pre[q] * pre[q]; }
      ms *= (1.f / 9.f);
      float r = 1.f / sqrtf(ms);
      float re = 1.f / sqrtf(emap[0]);
      #pragma unroll
      for (int q = 0; q < 9; q++)
        ws[FOFF_KK + q * 512 + (c0 + t)] = pre[q] * r * ws[FOFF_GAUSS + q] * re;
    }
  }
}

// ---------- K4 v2: modulated weights, 4 waves/block (one o per wave) ----------
__global__ void k_wb(const float* __restrict__ sw, const float* __restrict__ ws,
                     u16* __restrict__ wb) {
  int wv = threadIdx.x >> 6, lane = threadIdx.x & 63;
  int o = blockIdx.x * 4 + wv, b = blockIdx.y;
  float ssum = 0.f;
  #pragma unroll
  for (int i = 0; i < 8; i++) ssum += ws[FOFF_PART + i];
  float rsn = 1.f / sqrtf(ssum * (1.f / 4096.f));
  float swv[8], stv[8];
  float s2 = 0.f;
  #pragma unroll
  for (int q = 0; q < 8; q++) {
    int i = lane + q * 64;
    swv[q] = sw[(size_t)o * 512 + i];
    stv[q] = ws[FOFF_STYLES + b * 512 + i];
    s2 += swv[q] * swv[q];
  }
  for (int m = 32; m; m >>= 1) s2 += __shfl_xor(s2, m);
  float r1 = 1.f / sqrtf(s2 * (1.f / 512.f));
  float tv[8]; float t2 = 0.f;
  #pragma unroll
  for (int q = 0; q < 8; q++) { tv[q] = swv[q] * r1 * stv[q] * rsn; t2 += tv[q] * tv[q]; }
  for (int m = 32; m; m >>= 1) t2 += __shfl_xor(t2, m);
  float r2 = 1.f / sqrtf(t2 + 1e-8f);
  #pragma unroll
  for (int q = 0; q < 8; q++)
    wb[((size_t)b * 512 + o) * 512 + lane + q * 64] = f2b(tv[q] * r2);
}

// ---------- K5: transpose+cast ----------
__global__ void k_transpose(const float* __restrict__ x, u16* __restrict__ xT) {
  int h = blockIdx.x, c0 = blockIdx.y * 64, b = blockIdx.z;
  int t = threadIdx.x;
  __shared__ u16 tl[64][66];
  int wcol = t & 63, cbase = t >> 6;
  const float* xp = x + ((size_t)(b * 512 + c0)) * 4096 + h * 64;
  #pragma unroll
  for (int k = 0; k < 16; k++) {
    int ci = cbase + k * 4;
    tl[ci][wcol] = f2b(xp[(size_t)ci * 4096 + wcol]);
  }
  __syncthreads();
  int cp = t & 31, wbse = t >> 5;
  u32* dst = (u32*)(xT + ((size_t)b * 4096 + h * 64) * 512 + c0);
  #pragma unroll
  for (int k = 0; k < 8; k++) {
    int w_ = wbse + k * 8;
    u32 v0 = tl[cp * 2][w_], v1 = tl[cp * 2 + 1][w_];
    dst[w_ * 256 + cp] = v0 | (v1 << 16);
  }
}

// ---------- K6: depthwise 3x3, registers-only ----------
__global__ void k_dw(const u16* __restrict__ xT, const float* __restrict__ ws,
                     u16* __restrict__ y1) {
  int tile = blockIdx.x, b = blockIdx.y, t = threadIdx.x;
  int c2 = t * 2;
  float2 kk[9];
  #pragma unroll
  for (int q = 0; q < 9; q++) kk[q] = *(const float2*)&ws[FOFF_KK + q * 512 + c2];
  #pragma unroll 2
  for (int pos = 0; pos < 16; pos++) {
    int hw = tile * 16 + pos;
    if (hw < 4356) {
      int h = hw / 66, w_ = hw - h * 66;
      float a0 = 0.f, a1 = 0.f;
      for (int i = 0; i < 3; i++) {
        int ih = h - 2 + i; if (ih < 0 || ih >= 64) continue;
        for (int j = 0; j < 3; j++) {
          int iw = w_ - 2 + j; if (iw < 0 || iw >= 64) continue;
          u32 xv = *(const u32*)(xT + ((size_t)b * 4096 + ih * 64 + iw) * 512 + c2);
          float2 kv = kk[i * 3 + j];
          a0 += kv.x * b2f((u16)xv);
          a1 += kv.y * b2f((u16)(xv >> 16));
        }
      }
      ((u32*)y1)[(((size_t)b * 4480 + hw) * 512 + c2) >> 1] = (u32)f2b(a0) | ((u32)f2b(a1) << 16);
    } else {
      ((u32*)y1)[(((size_t)b * 4480 + hw) * 512 + c2) >> 1] = 0u;
    }
  }
}

// ---------- K7: batched GEMM, XCD-aware remap ----------
__launch_bounds__(256, 4)
__global__ void k_gemm(const u16* __restrict__ wbm, const u16* __restrict__ y1,
                       const float* __restrict__ bias, u16* __restrict__ y2) {
  int lid = blockIdx.x + 35 * (blockIdx.y + (blockIdx.z << 2));
  int b  = lid & 7;
  int s_ = lid >> 3;
  int mt = s_ & 3;
  int nt = s_ >> 2;
  int t = threadIdx.x, lane = t & 63, wv = t >> 6;
  int wm = wv >> 1, wn = wv & 1;
  __shared__ u16 Al[4096];
  __shared__ u16 Bl[4096];
  f32x4 acc[4][4];
  #pragma unroll
  for (int i = 0; i < 4; i++)
    #pragma unroll
    for (int j = 0; j < 4; j++)
      acc[i][j] = (f32x4){0.f, 0.f, 0.f, 0.f};

  const size_t Abase = (size_t)b * 512 + mt * 128;
  const size_t Bbase = (size_t)b * 4480 + nt * 128;
  int lrow = lane >> 2, dch = lane & 3;
  int cp = lane >> 4;

  for (int ks = 0; ks < 16; ks++) {
    int k0 = ks * 32;
    __syncthreads();
    #pragma unroll
    for (int half = 0; half < 2; half++) {
      int rbase = half * 64 + wv * 16;
      int row = rbase + lrow;
      int gch = dch ^ ((row >> 1) & 3);
      const u16* ga = wbm + (Abase + row) * 512 + k0 + gch * 8;
      const u16* gb = y1 + (Bbase + row) * 512 + k0 + gch * 8;
      __builtin_amdgcn_global_load_lds((const gu32*)ga, (lu32*)&Al[rbase * 32], 16, 0, 0);
      __builtin_amdgcn_global_load_lds((const gu32*)gb, (lu32*)&Bl[rbase * 32], 16, 0, 0);
    }
    asm volatile("s_waitcnt vmcnt(0)" ::: "memory");
    __syncthreads();
    bf16x8 af[4], bfr[4];
    #pragma unroll
    for (int mi = 0; mi < 4; mi++) {
      int row = wm * 64 + mi * 16 + (lane & 15);
      af[mi] = *(const bf16x8*)&Al[row * 32 + ((cp ^ ((row >> 1) & 3)) * 8)];
    }
    #pragma unroll
    for (int ni = 0; ni < 4; ni++) {
      int row = wn * 64 + ni * 16 + (lane & 15);
      bfr[ni] = *(const bf16x8*)&Bl[row * 32 + ((cp ^ ((row >> 1) & 3)) * 8)];
    }
    #pragma unroll
    for (int mi = 0; mi < 4; mi++)
      #pragma unroll
      for (int ni = 0; ni < 4; ni++)
        acc[mi][ni] = __builtin_amdgcn_mfma_f32_16x16x32_bf16(af[mi], bfr[ni], acc[mi][ni], 0, 0, 0);
  }
  int col0 = nt * 128 + wn * 64 + (lane & 15);
  int rb = (lane >> 4) * 4;
  #pragma unroll
  for (int mi = 0; mi < 4; mi++) {
    #pragma unroll
    for (int j = 0; j < 4; j++) {
      int o = mt * 128 + wm * 64 + mi * 16 + rb + j;
      float bv = bias[o];
      size_t rowoff = ((size_t)b * 512 + o) * 4480;
      #pragma unroll
      for (int ni = 0; ni < 4; ni++)
        y2[rowoff + col0 + ni * 16] = f2b(acc[mi][ni][j] + bv);
    }
  }
}

// ---------- K8 v10 (R14-verified 132us): v8 layout + setprio ----------
// Strides (u16): Yt 40, T1u 104, At 72, T3u 168
// LDS 30720 B: region1 @0 (20736): Yt[80][40] -> At[144][72] ; region2 @20736 (9984): T1u[48][104] -> T3u[16][168]
__launch_bounds__(256, 5)
__global__ void k_updown(const u16* __restrict__ y2,
                         const u16* __restrict__ muv, const u16* __restrict__ muh,
                         const u16* __restrict__ mdv, const u16* __restrict__ mdh,
                         float* __restrict__ out) {
  int g = blockIdx.x, o = blockIdx.y, b = blockIdx.z;
  int t = threadIdx.x, lane = t & 63, wv = t >> 6;
  int l15 = lane & 15, cp = lane >> 4, rb = cp * 4;
  __shared__ __align__(16) char smem[30720];
  u16* Yt  = (u16*)smem;             // [80][40]   (dead after S1)
  u16* At  = (u16*)smem;             // [144][72]  (aliases Yt; written in S2)
  u16* T1u = (u16*)(smem + 20736);   // [48][104]  (dead after S2)
  u16* T3u = (u16*)(smem + 20736);   // [16][168]  (aliases T1u)
  const int out_r0 = g * 16;
  const int yrow0 = out_r0 - 4;
  const u16* plane = y2 + ((size_t)b * 512 + o) * 4480;

  // zero all LDS (pads must be 0; aliased stale regions are only ever x0 by coeff zero-pads)
  for (int i = t; i < 1920; i += 256) ((float4*)smem)[i] = make_float4(0.f, 0.f, 0.f, 0.f);
  __syncthreads();
  // stage Y transposed: Yt[j][s] = y[yrow0+s][j]
  for (int idx = t; idx < 26 * 66; idx += 256) {
    int s = idx / 66, j = idx - 66 * s;
    int grow = yrow0 + s;
    u16 v = 0;
    if (grow >= 0 && grow < 66) v = plane[(size_t)grow * 66 + j];
    Yt[j * 40 + s] = v;
  }
  __syncthreads();

  // S1: T1(48x80) = Uv(48x32) x Yt^T   (1 k-step)
  __builtin_amdgcn_s_setprio(1);
  for (int tau = wv; tau < 15; tau += 4) {
    int mi = tau / 5, ni = tau - mi * 5;
    bf16x8 a = *(const bf16x8*)&muv[(mi * 16 + l15) * 32 + cp * 8];
    bf16x8 bfr = *(const bf16x8*)&Yt[(ni * 16 + l15) * 40 + cp * 8];
    f32x4 acc = (f32x4){0.f, 0.f, 0.f, 0.f};
    acc = __builtin_amdgcn_mfma_f32_16x16x32_bf16(a, bfr, acc, 0, 0, 0);
    #pragma unroll
    for (int j = 0; j < 4; j++)
      T1u[(mi * 16 + rb + j) * 104 + ni * 16 + l15] = f2b(acc[j]);
  }
  __builtin_amdgcn_s_setprio(0);
  __syncthreads();

  // S2: T2(48x144) = T1(48x96) x Uh^T ; act ; store transposed At[c][r] (packed 8B)
  __builtin_amdgcn_s_setprio(1);
  for (int ni = wv; ni < 9; ni += 4) {
    bf16x8 bh[3];
    #pragma unroll
    for (int ks = 0; ks < 3; ks++)
      bh[ks] = *(const bf16x8*)&muh[(ni * 16 + l15) * 96 + ks * 32 + cp * 8];
    #pragma unroll
    for (int mi = 0; mi < 3; mi++) {
      f32x4 acc = (f32x4){0.f, 0.f, 0.f, 0.f};
      #pragma unroll
      for (int ks = 0; ks < 3; ks++) {
        bf16x8 a = *(const bf16x8*)&T1u[(mi * 16 + l15) * 104 + ks * 32 + cp * 8];
        acc = __builtin_amdgcn_mfma_f32_16x16x32_bf16(a, bh[ks], acc, 0, 0, 0);
      }
      int c = ni * 16 + l15;
      u16 pv[4];
      #pragma unroll
      for (int j = 0; j < 4; j++) {
        float x = acc[j];
        x = fmaxf(x, 0.2f * x) * 5.65685424949238f;
        x = fminf(fmaxf(x, -256.f), 256.f);
        pv[j] = f2b(x);
      }
      u32 lo = (u32)pv[0] | ((u32)pv[1] << 16);
      u32 hi = (u32)pv[2] | ((u32)pv[3] << 16);
      *(uint2*)&At[c * 72 + mi * 16 + rb] = make_uint2(lo, hi);
    }
  }
  __builtin_amdgcn_s_setprio(0);
  __syncthreads();

  // S3: T3(16x144) = Dv(16x64) x At^T   (2 k-steps)
  __builtin_amdgcn_s_setprio(1);
  {
    bf16x8 a0 = *(const bf16x8*)&mdv[l15 * 64 + cp * 8];
    bf16x8 a1 = *(const bf16x8*)&mdv[l15 * 64 + 32 + cp * 8];
    for (int ni = wv; ni < 9; ni += 4) {
      f32x4 acc = (f32x4){0.f, 0.f, 0.f, 0.f};
      bf16x8 b0 = *(const bf16x8*)&At[(ni * 16 + l15) * 72 + cp * 8];
      acc = __builtin_amdgcn_mfma_f32_16x16x32_bf16(a0, b0, acc, 0, 0, 0);
      bf16x8 b1 = *(const bf16x8*)&At[(ni * 16 + l15) * 72 + 32 + cp * 8];
      acc = __builtin_amdgcn_mfma_f32_16x16x32_bf16(a1, b1, acc, 0, 0, 0);
      #pragma unroll
      for (int j = 0; j < 4; j++)
        T3u[(rb + j) * 168 + ni * 16 + l15] = f2b(acc[j]);
    }
  }
  __builtin_amdgcn_s_setprio(0);
  __syncthreads();

  // S4: OUT(16x64) = T3(16x160) x Dh^T  (5 k-steps), wave ni = wv
  {
    __builtin_amdgcn_s_setprio(1);
    f32x4 acc = (f32x4){0.f, 0.f, 0.f, 0.f};
    #pragma unroll
    for (int ks = 0; ks < 5; ks++) {
      bf16x8 a = *(const bf16x8*)&T3u[l15 * 168 + ks * 32 + cp * 8];
      bf16x8 bfr = *(const bf16x8*)&mdh[(wv * 16 + l15) * 160 + ks * 32 + cp * 8];
      acc = __builtin_amdgcn_mfma_f32_16x16x32_bf16(a, bfr, acc, 0, 0, 0);
    }
    __builtin_amdgcn_s_setprio(0);
    float* op = out + (((size_t)b * 512 + o) * 64 + out_r0) * 64;
    #pragma unroll
    for (int j = 0; j < 4; j++)
      op[(rb + j) * 64 + wv * 16 + l15] = acc[j];
  }
}

extern "C" void kernel_launch(void* const* d_in, const int* in_sizes, int n_in,
                              void* d_out, int out_size, void* d_ws, size_t ws_size,
                              hipStream_t stream) {
  const float* x     = (const float*)d_in[0];
  const float* w     = (const float*)d_in[1];
  const float* aw    = (const float*)d_in[2];
  const float* ab    = (const float*)d_in[3];
  const float* swgt  = (const float*)d_in[4];
  const float* bias  = (const float*)d_in[5];
  const float* sw0   = (const float*)d_in[6];
  const float* sb0   = (const float*)d_in[7];
  const float* sw1   = (const float*)d_in[8];
  const float* sb1   = (const float*)d_in[9];
  const float* sw2   = (const float*)d_in[10];
  const float* sb2   = (const float*)d_in[11];
  const float* sw3   = (const float*)d_in[12];
  const float* sb3   = (const float*)d_in[13];
  const float* kscl  = (const float*)d_in[14];
  const float* ema   = (const float*)d_in[15];

  float* ws  = (float*)d_ws;
  char*  wsb = (char*)d_ws;
  u16* wbp = (u16*)(wsb + OFFB_WB);
  u16* xT  = (u16*)(wsb + OFFB_XT);
  u16* y2  = xT;
  u16* y1  = (u16*)(wsb + OFFB_Y1);
  u16* muv = (u16*)(wsb + OFFB_MUV);
  u16* muh = (u16*)(wsb + OFFB_MUH);
  u16* mdv = (u16*)(wsb + OFFB_MDV);
  u16* mdh = (u16*)(wsb + OFFB_MDH);

  k_setup<<<dim3(1), dim3(256), 0, stream>>>(sw0, sb0, sw1, sb1, sw2, sb2, ws);
  k_stkw<<<dim3(72), dim3(256), 0, stream>>>(w, aw, ab, sw3, sb3, kscl, ema, ws);
  k_wb<<<dim3(128, 8), dim3(256), 0, stream>>>(swgt, ws, wbp);
  k_transpose<<<dim3(64, 8, 8), dim3(256), 0, stream>>>(x, xT);
  k_dw<<<dim3(280, 8), dim3(256), 0, stream>>>(xT, ws, y1);
  k_gemm<<<dim3(35, 4, 8), dim3(256), 0, stream>>>(wbp, y1, bias, y2);
  k_updown<<<dim3(4, 512, 8), dim3(256), 0, stream>>>(y2, muv, muh, mdv, mdh, (float*)d_out);
}

// Round 18
// 253.155 us; speedup vs baseline: 1.3027x; 1.1875x over previous
//
#include <hip/hip_runtime.h>
#include <stdint.h>
#include <math.h>

typedef uint16_t u16; typedef uint32_t u32;
typedef __bf16 bf16x8 __attribute__((ext_vector_type(8)));
typedef float  f32x4  __attribute__((ext_vector_type(4)));
typedef u32 __attribute__((address_space(1))) gu32;
typedef u32 __attribute__((address_space(3))) lu32;

// ---- ws layout ----
#define FOFF_FUP    0        // 12 floats (up==down filter)
#define FOFF_KG     16       // 4
#define FOFF_GAUSS  24       // 9
#define FOFF_PART   40       // 8 per-batch styles^2 partial sums
#define FOFF_H3     48       // 36*64
#define FOFF_STYLES 2368     // 8*512
#define FOFF_KK     6464     // 9*512  (tap-major)
#define OFFB_WB  ((size_t)65536)          // 8*512*512 bf16 = 4MB (ends 4259840)
#define OFFB_MUV ((size_t)4456448)        // Uv[48][32]  = 3072 B
#define OFFB_MUH ((size_t)4459520)        // Uh[144][96] = 27648 B
#define OFFB_MDV ((size_t)4487168)        // Dv[16][64]  = 2048 B
#define OFFB_MDH ((size_t)4489216)        // Dh[64][160] = 20480 B
#define OFFB_Y2  ((size_t)(8u<<20))       // 8*512*4480 bf16 = 35MB (was xT region)
#define OFFB_Y1  ((size_t)(45u<<20))      // 8*4480*512 bf16 = 35MB

static __device__ __forceinline__ u16 f2b(float f) {
  union { float f; u32 u; } v; v.f = f;
  u32 u = v.u;
  return (u16)((u + 0x7fffu + ((u >> 16) & 1u)) >> 16);
}
static __device__ __forceinline__ float b2f(u16 h) {
  union { u32 u; float f; } v; v.u = ((u32)h) << 16; return v.f;
}

// ---------- float filter construction (pipeline is bf16; 1e-6 rel error negligible) ----------
static __device__ float bessel_i0f(float x) {
  float t = x * 0.5f, t2 = t * t;
  float term = 1.f, sum = 1.f;
  for (int k = 1; k < 32; k++) {
    term *= t2 / ((float)k * (float)k);
    sum += term;
    if (term < 1e-8f * sum) break;
  }
  return sum;
}
static __device__ void firwin_devf(int numtaps, float cutoff, float width, float fs, float* out) {
  float nyq = fs * 0.5f;
  float atten = 2.285f * (numtaps - 1) * 3.14159265358979f * (width / nyq) + 7.95f;
  float beta;
  if (atten > 50.f) beta = 0.1102f * (atten - 8.7f);
  else if (atten > 21.f) beta = 0.5842f * powf(atten - 21.f, 0.4f) + 0.07886f * (atten - 21.f);
  else beta = 0.f;
  float c = cutoff / nyq;
  float i0b = bessel_i0f(beta);
  float h[16]; float s = 0.f;
  for (int n = 0; n < numtaps; n++) {
    float m = n - (numtaps - 1) * 0.5f;
    float x = c * m;
    float pix = 3.14159265358979f * x;
    float snc = (x == 0.f) ? 1.f : __sinf(pix) / pix;
    float r = 2.f * n / (float)(numtaps - 1) - 1.f;
    float arg = 1.f - r * r; if (arg < 0.f) arg = 0.f;
    float kais = bessel_i0f(beta * sqrtf(arg)) / i0b;
    h[n] = c * snc * kais; s += h[n];
  }
  for (int n = 0; n < numtaps; n++) out[n] = h[n] / s;
}

// ---------- K1: filters + gauss + SIREN h3 + MFMA filter matrices ----------
__global__ void k_setup(const float* __restrict__ sw0, const float* __restrict__ sb0,
                        const float* __restrict__ sw1, const float* __restrict__ sb1,
                        const float* __restrict__ sw2, const float* __restrict__ sb2,
                        float* __restrict__ ws) {
  __shared__ float hA[2304], hB[2304];
  int t = threadIdx.x;
  if (t == 0) {
    firwin_devf(12, 32.f, 2.f * 32.f * 0.41421356237309515f, 128.f, ws + FOFF_FUP);
  }
  if (t == 64) {
    float kc = 1.5f;
    firwin_devf(4, kc, 2.f * kc * 0.41421356237309515f, kc * 2.f * 1.0717734625362931f, ws + FOFF_KG);
  }
  if (t == 128) {
    float s2 = 0.5f;
    float gk[3];
    for (int k = 0; k < 3; k++) {
      float kn = (float)(k - 1);
      gk[k] = expf(-kn * kn / (2.f * s2)) / sqrtf(2.f * 3.14159265358979f * s2);
    }
    for (int i = 0; i < 3; i++)
      for (int j = 0; j < 3; j++)
        ws[FOFF_GAUSS + i * 3 + j] = sqrtf(gk[i] * gk[j]) * 2.f;
  }
  if (t >= 192 && t < 200) ws[FOFF_PART + t - 192] = 0.f;
  for (int idx = t; idx < 2304; idx += 256) {
    int p = idx >> 6, u = idx & 63;
    float gx = (2.f * (p % 6) + 1.f) / 6.f - 1.f;
    float gy = (2.f * (p / 6) + 1.f) / 6.f - 1.f;
    hA[idx] = sinf(30.f * (gx * sw0[u] + gy * sw0[64 + u] + sb0[u]));
  }
  __syncthreads();   // fu now visible to all threads
  {
    float fuv[12];
    #pragma unroll
    for (int i = 0; i < 12; i++) fuv[i] = ws[FOFF_FUP + i];
    char* wsb = (char*)ws;
    u16* muv = (u16*)(wsb + OFFB_MUV);
    u16* muh = (u16*)(wsb + OFFB_MUH);
    u16* mdv = (u16*)(wsb + OFFB_MDV);
    u16* mdh = (u16*)(wsb + OFFB_MDH);
    for (int i = t; i < 48 * 32; i += 256) {       // Uv[r][s]
      int r = i >> 5, s = i & 31;
      float v = 0.f;
      if (r < 42 && s < 26) {
        int d = (r >> 1) + 5 - s;
        if (d >= 0 && d <= 5) v = fuv[2 * d + (r & 1)];
      }
      muv[i] = f2b(v);
    }
    for (int i = t; i < 144 * 96; i += 256) {      // Uh[n][j]
      int n = i / 96, j = i - n * 96;
      float v = 0.f;
      if (n < 138 && j < 66) {
        int k = (n >> 1) + 1 - j;
        if (k >= 0 && k <= 5) v = fuv[2 * k + (n & 1)];
      }
      muh[i] = f2b(v);
    }
    for (int i = t; i < 16 * 64; i += 256) {       // Dv[R][ar]
      int R = i >> 6, ar = i & 63;
      float v = 0.f;
      if (ar < 42) {
        int q = ar - 2 * R;
        if (q >= 0 && q <= 11) v = fuv[11 - q];
      }
      mdv[i] = f2b(v);
    }
    for (int i = t; i < 64 * 160; i += 256) {      // Dh[ox][ac]
      int ox = i / 160, ac = i - ox * 160;
      float v = 0.f;
      if (ac < 138) {
        int q = ac - 2 * ox;
        if (q >= 0 && q <= 11) v = fuv[11 - q];
      }
      mdh[i] = f2b(v);
    }
  }
  for (int idx = t; idx < 2304; idx += 256) {
    int p = idx >> 6, u = idx & 63;
    float acc = sb1[u];
    for (int v = 0; v < 64; v++) acc += hA[p * 64 + v] * sw1[v * 64 + u];
    hB[idx] = sinf(acc);
  }
  __syncthreads();
  for (int idx = t; idx < 2304; idx += 256) {
    int p = idx >> 6, u = idx & 63;
    float acc = sb2[u];
    for (int v = 0; v < 64; v++) acc += hB[p * 64 + v] * sw2[v * 64 + u];
    ws[FOFF_H3 + idx] = sinf(acc);
  }
}

// ---------- K2+K3 merged: blocks 0..63 styles, 64..71 depthwise-kernel construction ----------
__global__ void k_stkw(const float* __restrict__ w, const float* __restrict__ aw,
                       const float* __restrict__ ab,
                       const float* __restrict__ w3, const float* __restrict__ b3,
                       const float* __restrict__ kscale, const float* __restrict__ emap,
                       float* __restrict__ ws) {
  __shared__ __align__(16) char sm[18944];
  int t = threadIdx.x;
  if (blockIdx.x < 64) {
    float* wl  = (float*)sm;          // [512]
    float* red = (float*)(sm + 2048); // [256]
    int b = blockIdx.x >> 3, j0 = (blockIdx.x & 7) * 64;
    wl[t] = w[b * 512 + t]; wl[t + 256] = w[b * 512 + 256 + t];
    __syncthreads();
    int j = j0 + (t & 63), kq = t >> 6;
    const f32x4* ar = (const f32x4*)(aw + (size_t)j * 512 + kq * 128);
    const f32x4* wv = (const f32x4*)(wl + kq * 128);
    float acc = 0.f;
    for (int k = 0; k < 32; k++) {
      f32x4 a = ar[k], c = wv[k];
      acc += a[0] * c[0] + a[1] * c[1] + a[2] * c[2] + a[3] * c[3];
    }
    red[t] = acc; __syncthreads();
    if (t < 64) {
      float sv = (red[t] + red[t + 64] + red[t + 128] + red[t + 192]) * 0.04419417382415922f + ab[j0 + t];
      ws[FOFF_STYLES + b * 512 + j0 + t] = sv;
      float p = sv * sv;
      for (int m = 32; m; m >>= 1) p += __shfl_xor(p, m);
      if (t == 0) atomicAdd(&ws[FOFF_PART + b], p);
    }
  } else {
    float* h3l = (float*)sm;            // [2304]
    float (*kw6)[37] = (float(*)[37])(sm + 9216);  // [64][37]
    int c0 = (blockIdx.x - 64) * 64;
    for (int i = t; i < 2304; i += 256) h3l[i] = ws[FOFF_H3 + i];
    __syncthreads();
    int cl = t & 63, pg = t >> 6;
    int c = c0 + cl;
    float acc[9];
    #pragma unroll
    for (int q = 0; q < 9; q++) acc[q] = b3[c];
    for (int v = 0; v < 64; v++) {
      float wv = w3[v * 512 + c];
      #pragma unroll
      for (int q = 0; q < 9; q++) acc[q] += h3l[(pg * 9 + q) * 64 + v] * wv;
    }
    float sc = 2.f / (1.f + expf(-kscale[c] * 0.1f));
    #pragma unroll
    for (int q = 0; q < 9; q++) kw6[cl][pg * 9 + q] = acc[q] * sc;
    __syncthreads();
    if (t < 64) {
      float kg[4];
      #pragma unroll
      for (int i = 0; i < 4; i++) kg[i] = ws[FOFF_KG + i];
      float pre[9];
      for (int u = 0; u < 3; u++)
        for (int vv = 0; vv < 3; vv++) {
          float s = 0.f;
          for (int t1 = 0; t1 < 4; t1++) {
            int a = 2 * u + t1 - 1;
            if (a < 0 || a > 5) continue;
            for (int t2 = 0; t2 < 4; t2++) {
              int bb = 2 * vv + t2 - 1;
              if (bb < 0 || bb > 5) continue;
              s += kg[3 - t1] * kg[3 - t2] * kw6[t][a * 6 + bb];
            }
          }
          pre[u * 3 + vv] = s;
        }
      float m = 0.f;
      #pragma unroll
      for (int q = 0; q < 9; q++) m += pre[q];
      m *= (1.f / 9.f);
      float ms = 0.f;
      #pragma unroll
      for (int q = 0; q < 9; q++) { pre[q] -= m; ms += pre[q] * pre[q]; }
      ms *= (1.f / 9.f);
      float r = 1.f / sqrtf(ms);
      float re = 1.f / sqrtf(emap[0]);
      #pragma unroll
      for (int q = 0; q < 9; q++)
        ws[FOFF_KK + q * 512 + (c0 + t)] = pre[q] * r * ws[FOFF_GAUSS + q] * re;
    }
  }
}

// ---------- K4 v2: modulated weights, 4 waves/block (one o per wave) ----------
__global__ void k_wb(const float* __restrict__ sw, const float* __restrict__ ws,
                     u16* __restrict__ wb) {
  int wv = threadIdx.x >> 6, lane = threadIdx.x & 63;
  int o = blockIdx.x * 4 + wv, b = blockIdx.y;
  float ssum = 0.f;
  #pragma unroll
  for (int i = 0; i < 8; i++) ssum += ws[FOFF_PART + i];
  float rsn = 1.f / sqrtf(ssum * (1.f / 4096.f));
  float swv[8], stv[8];
  float s2 = 0.f;
  #pragma unroll
  for (int q = 0; q < 8; q++) {
    int i = lane + q * 64;
    swv[q] = sw[(size_t)o * 512 + i];
    stv[q] = ws[FOFF_STYLES + b * 512 + i];
    s2 += swv[q] * swv[q];
  }
  for (int m = 32; m; m >>= 1) s2 += __shfl_xor(s2, m);
  float r1 = 1.f / sqrtf(s2 * (1.f / 512.f));
  float tv[8]; float t2 = 0.f;
  #pragma unroll
  for (int q = 0; q < 8; q++) { tv[q] = swv[q] * r1 * stv[q] * rsn; t2 += tv[q] * tv[q]; }
  for (int m = 32; m; m >>= 1) t2 += __shfl_xor(t2, m);
  float r2 = 1.f / sqrtf(t2 + 1e-8f);
  #pragma unroll
  for (int q = 0; q < 8; q++)
    wb[((size_t)b * 512 + o) * 512 + lane + q * 64] = f2b(tv[q] * r2);
}

// ---------- K5+K6 fused: transpose-cast + depthwise 3x3 in one pass ----------
// grid (67, 8, 8): h-row 0..65 compute; h==66 zero-fills y1 padding rows.
// LDS xl[i][wslot][c]: 3 x 68 x 64 u16 = 26112 B. Same bf16 rounding + tap order as the
// old two-kernel path -> y1 bit-identical.
__global__ void k_tdw(const float* __restrict__ x, const float* __restrict__ ws,
                      u16* __restrict__ y1) {
  int h = blockIdx.x, cb = blockIdx.y, b = blockIdx.z;
  int c0 = cb * 64, t = threadIdx.x;
  if (h == 66) {  // zero y1 rows 4356..4479 for this (c-slice, b)
    u32* dst = (u32*)y1;
    for (int idx = t; idx < 124 * 32; idx += 256) {
      int row = idx >> 5, col = idx & 31;
      dst[((size_t)b * 4480 + 4356 + row) * 256 + (c0 >> 1) + col] = 0u;
    }
    return;
  }
  __shared__ u16 xl[3 * 68 * 64];
  // pad cols wslot {0,1,66,67} = 0
  for (int idx = t; idx < 3 * 4 * 64; idx += 256) {
    int i = idx >> 8, r = idx & 255;
    int wsl = r >> 6; wsl = (wsl < 2) ? wsl : (64 + wsl);  // 0,1,66,67
    xl[i * 4352 + wsl * 64 + (r & 63)] = 0;
  }
  // stage rows: slot -> (c = slot&63, ri = slot>>6 -> i = ri>>2, q = ri&3); 16 f32 each
  for (int slot = t; slot < 768; slot += 256) {
    int c = slot & 63, ri = slot >> 6;
    int i = ri >> 2, q = ri & 3;
    int ih = h - 2 + i;
    u16* dst = &xl[i * 4352 + (2 + q * 16) * 64 + c];
    if (ih >= 0 && ih < 64) {
      const float* xp = x + ((size_t)(b * 512 + c0 + c)) * 4096 + ih * 64 + q * 16;
      #pragma unroll
      for (int k = 0; k < 16; k++) dst[k * 64] = f2b(xp[k]);
    } else {
      #pragma unroll
      for (int k = 0; k < 16; k++) dst[k * 64] = 0;
    }
  }
  __syncthreads();
  // compute: thread = (c2i = t&31, wg = t>>5); 9 taps, same (i,j) order as old k_dw
  int c2i = t & 31, wg = t >> 5;
  int c2 = 2 * c2i;
  float2 kk[9];
  #pragma unroll
  for (int q = 0; q < 9; q++) kk[q] = *(const float2*)&ws[FOFF_KK + q * 512 + c0 + c2];
  for (int w_ = wg; w_ < 66; w_ += 8) {
    float a0 = 0.f, a1 = 0.f;
    #pragma unroll
    for (int i = 0; i < 3; i++) {
      #pragma unroll
      for (int j = 0; j < 3; j++) {
        u32 xv = *(const u32*)&xl[i * 4352 + (w_ + j) * 64 + c2];
        float2 kv = kk[i * 3 + j];
        a0 += kv.x * b2f((u16)xv);
        a1 += kv.y * b2f((u16)(xv >> 16));
      }
    }
    ((u32*)y1)[(((size_t)b * 4480 + h * 66 + w_) * 512 + c0 + c2) >> 1] =
        (u32)f2b(a0) | ((u32)f2b(a1) << 16);
  }
}

// ---------- K7: batched GEMM, XCD-aware remap ----------
__launch_bounds__(256, 4)
__global__ void k_gemm(const u16* __restrict__ wbm, const u16* __restrict__ y1,
                       const float* __restrict__ bias, u16* __restrict__ y2) {
  int lid = blockIdx.x + 35 * (blockIdx.y + (blockIdx.z << 2));
  int b  = lid & 7;
  int s_ = lid >> 3;
  int mt = s_ & 3;
  int nt = s_ >> 2;
  int t = threadIdx.x, lane = t & 63, wv = t >> 6;
  int wm = wv >> 1, wn = wv & 1;
  __shared__ u16 Al[4096];
  __shared__ u16 Bl[4096];
  f32x4 acc[4][4];
  #pragma unroll
  for (int i = 0; i < 4; i++)
    #pragma unroll
    for (int j = 0; j < 4; j++)
      acc[i][j] = (f32x4){0.f, 0.f, 0.f, 0.f};

  const size_t Abase = (size_t)b * 512 + mt * 128;
  const size_t Bbase = (size_t)b * 4480 + nt * 128;
  int lrow = lane >> 2, dch = lane & 3;
  int cp = lane >> 4;

  for (int ks = 0; ks < 16; ks++) {
    int k0 = ks * 32;
    __syncthreads();
    #pragma unroll
    for (int half = 0; half < 2; half++) {
      int rbase = half * 64 + wv * 16;
      int row = rbase + lrow;
      int gch = dch ^ ((row >> 1) & 3);
      const u16* ga = wbm + (Abase + row) * 512 + k0 + gch * 8;
      const u16* gb = y1 + (Bbase + row) * 512 + k0 + gch * 8;
      __builtin_amdgcn_global_load_lds((const gu32*)ga, (lu32*)&Al[rbase * 32], 16, 0, 0);
      __builtin_amdgcn_global_load_lds((const gu32*)gb, (lu32*)&Bl[rbase * 32], 16, 0, 0);
    }
    asm volatile("s_waitcnt vmcnt(0)" ::: "memory");
    __syncthreads();
    bf16x8 af[4], bfr[4];
    #pragma unroll
    for (int mi = 0; mi < 4; mi++) {
      int row = wm * 64 + mi * 16 + (lane & 15);
      af[mi] = *(const bf16x8*)&Al[row * 32 + ((cp ^ ((row >> 1) & 3)) * 8)];
    }
    #pragma unroll
    for (int ni = 0; ni < 4; ni++) {
      int row = wn * 64 + ni * 16 + (lane & 15);
      bfr[ni] = *(const bf16x8*)&Bl[row * 32 + ((cp ^ ((row >> 1) & 3)) * 8)];
    }
    #pragma unroll
    for (int mi = 0; mi < 4; mi++)
      #pragma unroll
      for (int ni = 0; ni < 4; ni++)
        acc[mi][ni] = __builtin_amdgcn_mfma_f32_16x16x32_bf16(af[mi], bfr[ni], acc[mi][ni], 0, 0, 0);
  }
  int col0 = nt * 128 + wn * 64 + (lane & 15);
  int rb = (lane >> 4) * 4;
  #pragma unroll
  for (int mi = 0; mi < 4; mi++) {
    #pragma unroll
    for (int j = 0; j < 4; j++) {
      int o = mt * 128 + wm * 64 + mi * 16 + rb + j;
      float bv = bias[o];
      size_t rowoff = ((size_t)b * 512 + o) * 4480;
      #pragma unroll
      for (int ni = 0; ni < 4; ni++)
        y2[rowoff + col0 + ni * 16] = f2b(acc[mi][ni][j] + bv);
    }
  }
}

// ---------- K8 v10 (R14-verified 132us): v8 layout + setprio ----------
__launch_bounds__(256, 5)
__global__ void k_updown(const u16* __restrict__ y2,
                         const u16* __restrict__ muv, const u16* __restrict__ muh,
                         const u16* __restrict__ mdv, const u16* __restrict__ mdh,
                         float* __restrict__ out) {
  int g = blockIdx.x, o = blockIdx.y, b = blockIdx.z;
  int t = threadIdx.x, lane = t & 63, wv = t >> 6;
  int l15 = lane & 15, cp = lane >> 4, rb = cp * 4;
  __shared__ __align__(16) char smem[30720];
  u16* Yt  = (u16*)smem;             // [80][40]   (dead after S1)
  u16* At  = (u16*)smem;             // [144][72]  (aliases Yt; written in S2)
  u16* T1u = (u16*)(smem + 20736);   // [48][104]  (dead after S2)
  u16* T3u = (u16*)(smem + 20736);   // [16][168]  (aliases T1u)
  const int out_r0 = g * 16;
  const int yrow0 = out_r0 - 4;
  const u16* plane = y2 + ((size_t)b * 512 + o) * 4480;

  for (int i = t; i < 1920; i += 256) ((float4*)smem)[i] = make_float4(0.f, 0.f, 0.f, 0.f);
  __syncthreads();
  for (int idx = t; idx < 26 * 66; idx += 256) {
    int s = idx / 66, j = idx - 66 * s;
    int grow = yrow0 + s;
    u16 v = 0;
    if (grow >= 0 && grow < 66) v = plane[(size_t)grow * 66 + j];
    Yt[j * 40 + s] = v;
  }
  __syncthreads();

  __builtin_amdgcn_s_setprio(1);
  for (int tau = wv; tau < 15; tau += 4) {
    int mi = tau / 5, ni = tau - mi * 5;
    bf16x8 a = *(const bf16x8*)&muv[(mi * 16 + l15) * 32 + cp * 8];
    bf16x8 bfr = *(const bf16x8*)&Yt[(ni * 16 + l15) * 40 + cp * 8];
    f32x4 acc = (f32x4){0.f, 0.f, 0.f, 0.f};
    acc = __builtin_amdgcn_mfma_f32_16x16x32_bf16(a, bfr, acc, 0, 0, 0);
    #pragma unroll
    for (int j = 0; j < 4; j++)
      T1u[(mi * 16 + rb + j) * 104 + ni * 16 + l15] = f2b(acc[j]);
  }
  __builtin_amdgcn_s_setprio(0);
  __syncthreads();

  __builtin_amdgcn_s_setprio(1);
  for (int ni = wv; ni < 9; ni += 4) {
    bf16x8 bh[3];
    #pragma unroll
    for (int ks = 0; ks < 3; ks++)
      bh[ks] = *(const bf16x8*)&muh[(ni * 16 + l15) * 96 + ks * 32 + cp * 8];
    #pragma unroll
    for (int mi = 0; mi < 3; mi++) {
      f32x4 acc = (f32x4){0.f, 0.f, 0.f, 0.f};
      #pragma unroll
      for (int ks = 0; ks < 3; ks++) {
        bf16x8 a = *(const bf16x8*)&T1u[(mi * 16 + l15) * 104 + ks * 32 + cp * 8];
        acc = __builtin_amdgcn_mfma_f32_16x16x32_bf16(a, bh[ks], acc, 0, 0, 0);
      }
      int c = ni * 16 + l15;
      u16 pv[4];
      #pragma unroll
      for (int j = 0; j < 4; j++) {
        float x = acc[j];
        x = fmaxf(x, 0.2f * x) * 5.65685424949238f;
        x = fminf(fmaxf(x, -256.f), 256.f);
        pv[j] = f2b(x);
      }
      u32 lo = (u32)pv[0] | ((u32)pv[1] << 16);
      u32 hi = (u32)pv[2] | ((u32)pv[3] << 16);
      *(uint2*)&At[c * 72 + mi * 16 + rb] = make_uint2(lo, hi);
    }
  }
  __builtin_amdgcn_s_setprio(0);
  __syncthreads();

  __builtin_amdgcn_s_setprio(1);
  {
    bf16x8 a0 = *(const bf16x8*)&mdv[l15 * 64 + cp * 8];
    bf16x8 a1 = *(const bf16x8*)&mdv[l15 * 64 + 32 + cp * 8];
    for (int ni = wv; ni < 9; ni += 4) {
      f32x4 acc = (f32x4){0.f, 0.f, 0.f, 0.f};
      bf16x8 b0 = *(const bf16x8*)&At[(ni * 16 + l15) * 72 + cp * 8];
      acc = __builtin_amdgcn_mfma_f32_16x16x32_bf16(a0, b0, acc, 0, 0, 0);
      bf16x8 b1 = *(const bf16x8*)&At[(ni * 16 + l15) * 72 + 32 + cp * 8];
      acc = __builtin_amdgcn_mfma_f32_16x16x32_bf16(a1, b1, acc, 0, 0, 0);
      #pragma unroll
      for (int j = 0; j < 4; j++)
        T3u[(rb + j) * 168 + ni * 16 + l15] = f2b(acc[j]);
    }
  }
  __builtin_amdgcn_s_setprio(0);
  __syncthreads();

  {
    __builtin_amdgcn_s_setprio(1);
    f32x4 acc = (f32x4){0.f, 0.f, 0.f, 0.f};
    #pragma unroll
    for (int ks = 0; ks < 5; ks++) {
      bf16x8 a = *(const bf16x8*)&T3u[l15 * 168 + ks * 32 + cp * 8];
      bf16x8 bfr = *(const bf16x8*)&mdh[(wv * 16 + l15) * 160 + ks * 32 + cp * 8];
      acc = __builtin_amdgcn_mfma_f32_16x16x32_bf16(a, bfr, acc, 0, 0, 0);
    }
    __builtin_amdgcn_s_setprio(0);
    float* op = out + (((size_t)b * 512 + o) * 64 + out_r0) * 64;
    #pragma unroll
    for (int j = 0; j < 4; j++)
      op[(rb + j) * 64 + wv * 16 + l15] = acc[j];
  }
}

extern "C" void kernel_launch(void* const* d_in, const int* in_sizes, int n_in,
                              void* d_out, int out_size, void* d_ws, size_t ws_size,
                              hipStream_t stream) {
  const float* x     = (const float*)d_in[0];
  const float* w     = (const float*)d_in[1];
  const float* aw    = (const float*)d_in[2];
  const float* ab    = (const float*)d_in[3];
  const float* swgt  = (const float*)d_in[4];
  const float* bias  = (const float*)d_in[5];
  const float* sw0   = (const float*)d_in[6];
  const float* sb0   = (const float*)d_in[7];
  const float* sw1   = (const float*)d_in[8];
  const float* sb1   = (const float*)d_in[9];
  const float* sw2   = (const float*)d_in[10];
  const float* sb2   = (const float*)d_in[11];
  const float* sw3   = (const float*)d_in[12];
  const float* sb3   = (const float*)d_in[13];
  const float* kscl  = (const float*)d_in[14];
  const float* ema   = (const float*)d_in[15];

  float* ws  = (float*)d_ws;
  char*  wsb = (char*)d_ws;
  u16* wbp = (u16*)(wsb + OFFB_WB);
  u16* y2  = (u16*)(wsb + OFFB_Y2);
  u16* y1  = (u16*)(wsb + OFFB_Y1);
  u16* muv = (u16*)(wsb + OFFB_MUV);
  u16* muh = (u16*)(wsb + OFFB_MUH);
  u16* mdv = (u16*)(wsb + OFFB_MDV);
  u16* mdh = (u16*)(wsb + OFFB_MDH);

  k_setup<<<dim3(1), dim3(256), 0, stream>>>(sw0, sb0, sw1, sb1, sw2, sb2, ws);
  k_stkw<<<dim3(72), dim3(256), 0, stream>>>(w, aw, ab, sw3, sb3, kscl, ema, ws);
  k_wb<<<dim3(128, 8), dim3(256), 0, stream>>>(swgt, ws, wbp);
  k_tdw<<<dim3(67, 8, 8), dim3(256), 0, stream>>>(x, ws, y1);
  k_gemm<<<dim3(35, 4, 8), dim3(256), 0, stream>>>(wbp, y1, bias, y2);
  k_updown<<<dim3(4, 512, 8), dim3(256), 0, stream>>>(y2, muv, muh, mdv, mdh, (float*)d_out);
}

// Round 19
// 242.724 us; speedup vs baseline: 1.3587x; 1.0430x over previous
//
#include <hip/hip_runtime.h>
#include <stdint.h>
#include <math.h>

typedef uint16_t u16; typedef uint32_t u32;
typedef __bf16 bf16x8 __attribute__((ext_vector_type(8)));
typedef float  f32x4  __attribute__((ext_vector_type(4)));
typedef u32 __attribute__((address_space(1))) gu32;
typedef u32 __attribute__((address_space(3))) lu32;

// ---- ws layout ----
#define FOFF_FUP    0        // 12 floats (up==down filter)
#define FOFF_KG     16       // 4
#define FOFF_GAUSS  24       // 9
#define FOFF_PART   40       // 8 per-batch styles^2 partial sums
#define FOFF_H3     48       // 36*64
#define FOFF_STYLES 2368     // 8*512
#define FOFF_KK     6464     // 9*512  (tap-major)
#define OFFB_WB  ((size_t)65536)          // 8*512*512 bf16 = 4MB (ends 4259840)
#define OFFB_MUV ((size_t)4456448)        // Uv[48][32]  = 3072 B
#define OFFB_MUH ((size_t)4459520)        // Uh[144][96] = 27648 B
#define OFFB_MDV ((size_t)4487168)        // Dv[16][64]  = 2048 B
#define OFFB_MDH ((size_t)4489216)        // Dh[64][160] = 20480 B
#define OFFB_Y2  ((size_t)(8u<<20))       // 8*512*4480 bf16 = 35MB
#define OFFB_Y1  ((size_t)(45u<<20))      // 8*4480*512 bf16 = 35MB

static __device__ __forceinline__ u16 f2b(float f) {
  union { float f; u32 u; } v; v.f = f;
  u32 u = v.u;
  return (u16)((u + 0x7fffu + ((u >> 16) & 1u)) >> 16);
}
static __device__ __forceinline__ float b2f(u16 h) {
  union { u32 u; float f; } v; v.u = ((u32)h) << 16; return v.f;
}

// ---------- float filter construction ----------
static __device__ float bessel_i0f(float x) {
  float t = x * 0.5f, t2 = t * t;
  float term = 1.f, sum = 1.f;
  for (int k = 1; k < 32; k++) {
    term *= t2 / ((float)k * (float)k);
    sum += term;
    if (term < 1e-8f * sum) break;
  }
  return sum;
}
static __device__ void firwin_devf(int numtaps, float cutoff, float width, float fs, float* out) {
  float nyq = fs * 0.5f;
  float atten = 2.285f * (numtaps - 1) * 3.14159265358979f * (width / nyq) + 7.95f;
  float beta;
  if (atten > 50.f) beta = 0.1102f * (atten - 8.7f);
  else if (atten > 21.f) beta = 0.5842f * powf(atten - 21.f, 0.4f) + 0.07886f * (atten - 21.f);
  else beta = 0.f;
  float c = cutoff / nyq;
  float i0b = bessel_i0f(beta);
  float h[16]; float s = 0.f;
  for (int n = 0; n < numtaps; n++) {
    float m = n - (numtaps - 1) * 0.5f;
    float x = c * m;
    float pix = 3.14159265358979f * x;
    float snc = (x == 0.f) ? 1.f : __sinf(pix) / pix;
    float r = 2.f * n / (float)(numtaps - 1) - 1.f;
    float arg = 1.f - r * r; if (arg < 0.f) arg = 0.f;
    float kais = bessel_i0f(beta * sqrtf(arg)) / i0b;
    h[n] = c * snc * kais; s += h[n];
  }
  for (int n = 0; n < numtaps; n++) out[n] = h[n] / s;
}

// ---------- K1: filters + gauss + SIREN h3 + MFMA filter matrices ----------
__global__ void k_setup(const float* __restrict__ sw0, const float* __restrict__ sb0,
                        const float* __restrict__ sw1, const float* __restrict__ sb1,
                        const float* __restrict__ sw2, const float* __restrict__ sb2,
                        float* __restrict__ ws) {
  __shared__ float hA[2304], hB[2304];
  int t = threadIdx.x;
  if (t == 0) {
    firwin_devf(12, 32.f, 2.f * 32.f * 0.41421356237309515f, 128.f, ws + FOFF_FUP);
  }
  if (t == 64) {
    float kc = 1.5f;
    firwin_devf(4, kc, 2.f * kc * 0.41421356237309515f, kc * 2.f * 1.0717734625362931f, ws + FOFF_KG);
  }
  if (t == 128) {
    float s2 = 0.5f;
    float gk[3];
    for (int k = 0; k < 3; k++) {
      float kn = (float)(k - 1);
      gk[k] = expf(-kn * kn / (2.f * s2)) / sqrtf(2.f * 3.14159265358979f * s2);
    }
    for (int i = 0; i < 3; i++)
      for (int j = 0; j < 3; j++)
        ws[FOFF_GAUSS + i * 3 + j] = sqrtf(gk[i] * gk[j]) * 2.f;
  }
  if (t >= 192 && t < 200) ws[FOFF_PART + t - 192] = 0.f;
  for (int idx = t; idx < 2304; idx += 256) {
    int p = idx >> 6, u = idx & 63;
    float gx = (2.f * (p % 6) + 1.f) / 6.f - 1.f;
    float gy = (2.f * (p / 6) + 1.f) / 6.f - 1.f;
    hA[idx] = sinf(30.f * (gx * sw0[u] + gy * sw0[64 + u] + sb0[u]));
  }
  __syncthreads();   // fu now visible to all threads
  {
    float fuv[12];
    #pragma unroll
    for (int i = 0; i < 12; i++) fuv[i] = ws[FOFF_FUP + i];
    char* wsb = (char*)ws;
    u16* muv = (u16*)(wsb + OFFB_MUV);
    u16* muh = (u16*)(wsb + OFFB_MUH);
    u16* mdv = (u16*)(wsb + OFFB_MDV);
    u16* mdh = (u16*)(wsb + OFFB_MDH);
    for (int i = t; i < 48 * 32; i += 256) {       // Uv[r][s]
      int r = i >> 5, s = i & 31;
      float v = 0.f;
      if (r < 42 && s < 26) {
        int d = (r >> 1) + 5 - s;
        if (d >= 0 && d <= 5) v = fuv[2 * d + (r & 1)];
      }
      muv[i] = f2b(v);
    }
    for (int i = t; i < 144 * 96; i += 256) {      // Uh[n][j]
      int n = i / 96, j = i - n * 96;
      float v = 0.f;
      if (n < 138 && j < 66) {
        int k = (n >> 1) + 1 - j;
        if (k >= 0 && k <= 5) v = fuv[2 * k + (n & 1)];
      }
      muh[i] = f2b(v);
    }
    for (int i = t; i < 16 * 64; i += 256) {       // Dv[R][ar]
      int R = i >> 6, ar = i & 63;
      float v = 0.f;
      if (ar < 42) {
        int q = ar - 2 * R;
        if (q >= 0 && q <= 11) v = fuv[11 - q];
      }
      mdv[i] = f2b(v);
    }
    for (int i = t; i < 64 * 160; i += 256) {      // Dh[ox][ac]
      int ox = i / 160, ac = i - ox * 160;
      float v = 0.f;
      if (ac < 138) {
        int q = ac - 2 * ox;
        if (q >= 0 && q <= 11) v = fuv[11 - q];
      }
      mdh[i] = f2b(v);
    }
  }
  for (int idx = t; idx < 2304; idx += 256) {
    int p = idx >> 6, u = idx & 63;
    float acc = sb1[u];
    for (int v = 0; v < 64; v++) acc += hA[p * 64 + v] * sw1[v * 64 + u];
    hB[idx] = sinf(acc);
  }
  __syncthreads();
  for (int idx = t; idx < 2304; idx += 256) {
    int p = idx >> 6, u = idx & 63;
    float acc = sb2[u];
    for (int v = 0; v < 64; v++) acc += hB[p * 64 + v] * sw2[v * 64 + u];
    ws[FOFF_H3 + idx] = sinf(acc);
  }
}

// ---------- K2+K3 merged ----------
__global__ void k_stkw(const float* __restrict__ w, const float* __restrict__ aw,
                       const float* __restrict__ ab,
                       const float* __restrict__ w3, const float* __restrict__ b3,
                       const float* __restrict__ kscale, const float* __restrict__ emap,
                       float* __restrict__ ws) {
  __shared__ __align__(16) char sm[18944];
  int t = threadIdx.x;
  if (blockIdx.x < 64) {
    float* wl  = (float*)sm;          // [512]
    float* red = (float*)(sm + 2048); // [256]
    int b = blockIdx.x >> 3, j0 = (blockIdx.x & 7) * 64;
    wl[t] = w[b * 512 + t]; wl[t + 256] = w[b * 512 + 256 + t];
    __syncthreads();
    int j = j0 + (t & 63), kq = t >> 6;
    const f32x4* ar = (const f32x4*)(aw + (size_t)j * 512 + kq * 128);
    const f32x4* wv = (const f32x4*)(wl + kq * 128);
    float acc = 0.f;
    for (int k = 0; k < 32; k++) {
      f32x4 a = ar[k], c = wv[k];
      acc += a[0] * c[0] + a[1] * c[1] + a[2] * c[2] + a[3] * c[3];
    }
    red[t] = acc; __syncthreads();
    if (t < 64) {
      float sv = (red[t] + red[t + 64] + red[t + 128] + red[t + 192]) * 0.04419417382415922f + ab[j0 + t];
      ws[FOFF_STYLES + b * 512 + j0 + t] = sv;
      float p = sv * sv;
      for (int m = 32; m; m >>= 1) p += __shfl_xor(p, m);
      if (t == 0) atomicAdd(&ws[FOFF_PART + b], p);
    }
  } else {
    float* h3l = (float*)sm;            // [2304]
    float (*kw6)[37] = (float(*)[37])(sm + 9216);  // [64][37]
    int c0 = (blockIdx.x - 64) * 64;
    for (int i = t; i < 2304; i += 256) h3l[i] = ws[FOFF_H3 + i];
    __syncthreads();
    int cl = t & 63, pg = t >> 6;
    int c = c0 + cl;
    float acc[9];
    #pragma unroll
    for (int q = 0; q < 9; q++) acc[q] = b3[c];
    for (int v = 0; v < 64; v++) {
      float wv = w3[v * 512 + c];
      #pragma unroll
      for (int q = 0; q < 9; q++) acc[q] += h3l[(pg * 9 + q) * 64 + v] * wv;
    }
    float sc = 2.f / (1.f + expf(-kscale[c] * 0.1f));
    #pragma unroll
    for (int q = 0; q < 9; q++) kw6[cl][pg * 9 + q] = acc[q] * sc;
    __syncthreads();
    if (t < 64) {
      float kg[4];
      #pragma unroll
      for (int i = 0; i < 4; i++) kg[i] = ws[FOFF_KG + i];
      float pre[9];
      for (int u = 0; u < 3; u++)
        for (int vv = 0; vv < 3; vv++) {
          float s = 0.f;
          for (int t1 = 0; t1 < 4; t1++) {
            int a = 2 * u + t1 - 1;
            if (a < 0 || a > 5) continue;
            for (int t2 = 0; t2 < 4; t2++) {
              int bb = 2 * vv + t2 - 1;
              if (bb < 0 || bb > 5) continue;
              s += kg[3 - t1] * kg[3 - t2] * kw6[t][a * 6 + bb];
            }
          }
          pre[u * 3 + vv] = s;
        }
      float m = 0.f;
      #pragma unroll
      for (int q = 0; q < 9; q++) m += pre[q];
      m *= (1.f / 9.f);
      float ms = 0.f;
      #pragma unroll
      for (int q = 0; q < 9; q++) { pre[q] -= m; ms += pre[q] * pre[q]; }
      ms *= (1.f / 9.f);
      float r = 1.f / sqrtf(ms);
      float re = 1.f / sqrtf(emap[0]);
      #pragma unroll
      for (int q = 0; q < 9; q++)
        ws[FOFF_KK + q * 512 + (c0 + t)] = pre[q] * r * ws[FOFF_GAUSS + q] * re;
    }
  }
}

// ---------- K4 v2: modulated weights ----------
__global__ void k_wb(const float* __restrict__ sw, const float* __restrict__ ws,
                     u16* __restrict__ wb) {
  int wv = threadIdx.x >> 6, lane = threadIdx.x & 63;
  int o = blockIdx.x * 4 + wv, b = blockIdx.y;
  float ssum = 0.f;
  #pragma unroll
  for (int i = 0; i < 8; i++) ssum += ws[FOFF_PART + i];
  float rsn = 1.f / sqrtf(ssum * (1.f / 4096.f));
  float swv[8], stv[8];
  float s2 = 0.f;
  #pragma unroll
  for (int q = 0; q < 8; q++) {
    int i = lane + q * 64;
    swv[q] = sw[(size_t)o * 512 + i];
    stv[q] = ws[FOFF_STYLES + b * 512 + i];
    s2 += swv[q] * swv[q];
  }
  for (int m = 32; m; m >>= 1) s2 += __shfl_xor(s2, m);
  float r1 = 1.f / sqrtf(s2 * (1.f / 512.f));
  float tv[8]; float t2 = 0.f;
  #pragma unroll
  for (int q = 0; q < 8; q++) { tv[q] = swv[q] * r1 * stv[q] * rsn; t2 += tv[q] * tv[q]; }
  for (int m = 32; m; m >>= 1) t2 += __shfl_xor(t2, m);
  float r2 = 1.f / sqrtf(t2 + 1e-8f);
  #pragma unroll
  for (int q = 0; q < 8; q++)
    wb[((size_t)b * 512 + o) * 512 + lane + q * 64] = f2b(tv[q] * r2);
}

// ---------- K5+K6 fused: transpose-cast + depthwise 3x3 ----------
__global__ void k_tdw(const float* __restrict__ x, const float* __restrict__ ws,
                      u16* __restrict__ y1) {
  int h = blockIdx.x, cb = blockIdx.y, b = blockIdx.z;
  int c0 = cb * 64, t = threadIdx.x;
  if (h == 66) {
    u32* dst = (u32*)y1;
    for (int idx = t; idx < 124 * 32; idx += 256) {
      int row = idx >> 5, col = idx & 31;
      dst[((size_t)b * 4480 + 4356 + row) * 256 + (c0 >> 1) + col] = 0u;
    }
    return;
  }
  __shared__ u16 xl[3 * 68 * 64];
  for (int idx = t; idx < 3 * 4 * 64; idx += 256) {
    int i = idx >> 8, r = idx & 255;
    int wsl = r >> 6; wsl = (wsl < 2) ? wsl : (64 + wsl);
    xl[i * 4352 + wsl * 64 + (r & 63)] = 0;
  }
  for (int slot = t; slot < 768; slot += 256) {
    int c = slot & 63, ri = slot >> 6;
    int i = ri >> 2, q = ri & 3;
    int ih = h - 2 + i;
    u16* dst = &xl[i * 4352 + (2 + q * 16) * 64 + c];
    if (ih >= 0 && ih < 64) {
      const float* xp = x + ((size_t)(b * 512 + c0 + c)) * 4096 + ih * 64 + q * 16;
      #pragma unroll
      for (int k = 0; k < 16; k++) dst[k * 64] = f2b(xp[k]);
    } else {
      #pragma unroll
      for (int k = 0; k < 16; k++) dst[k * 64] = 0;
    }
  }
  __syncthreads();
  int c2i = t & 31, wg = t >> 5;
  int c2 = 2 * c2i;
  float2 kk[9];
  #pragma unroll
  for (int q = 0; q < 9; q++) kk[q] = *(const float2*)&ws[FOFF_KK + q * 512 + c0 + c2];
  for (int w_ = wg; w_ < 66; w_ += 8) {
    float a0 = 0.f, a1 = 0.f;
    #pragma unroll
    for (int i = 0; i < 3; i++) {
      #pragma unroll
      for (int j = 0; j < 3; j++) {
        u32 xv = *(const u32*)&xl[i * 4352 + (w_ + j) * 64 + c2];
        float2 kv = kk[i * 3 + j];
        a0 += kv.x * b2f((u16)xv);
        a1 += kv.y * b2f((u16)(xv >> 16));
      }
    }
    ((u32*)y1)[(((size_t)b * 4480 + h * 66 + w_) * 512 + c0 + c2) >> 1] =
        (u32)f2b(a0) | ((u32)f2b(a1) << 16);
  }
}

// ---------- K7: batched GEMM, XCD-aware remap ----------
__launch_bounds__(256, 4)
__global__ void k_gemm(const u16* __restrict__ wbm, const u16* __restrict__ y1,
                       const float* __restrict__ bias, u16* __restrict__ y2) {
  int lid = blockIdx.x + 35 * (blockIdx.y + (blockIdx.z << 2));
  int b  = lid & 7;
  int s_ = lid >> 3;
  int mt = s_ & 3;
  int nt = s_ >> 2;
  int t = threadIdx.x, lane = t & 63, wv = t >> 6;
  int wm = wv >> 1, wn = wv & 1;
  __shared__ u16 Al[4096];
  __shared__ u16 Bl[4096];
  f32x4 acc[4][4];
  #pragma unroll
  for (int i = 0; i < 4; i++)
    #pragma unroll
    for (int j = 0; j < 4; j++)
      acc[i][j] = (f32x4){0.f, 0.f, 0.f, 0.f};

  const size_t Abase = (size_t)b * 512 + mt * 128;
  const size_t Bbase = (size_t)b * 4480 + nt * 128;
  int lrow = lane >> 2, dch = lane & 3;
  int cp = lane >> 4;

  for (int ks = 0; ks < 16; ks++) {
    int k0 = ks * 32;
    __syncthreads();
    #pragma unroll
    for (int half = 0; half < 2; half++) {
      int rbase = half * 64 + wv * 16;
      int row = rbase + lrow;
      int gch = dch ^ ((row >> 1) & 3);
      const u16* ga = wbm + (Abase + row) * 512 + k0 + gch * 8;
      const u16* gb = y1 + (Bbase + row) * 512 + k0 + gch * 8;
      __builtin_amdgcn_global_load_lds((const gu32*)ga, (lu32*)&Al[rbase * 32], 16, 0, 0);
      __builtin_amdgcn_global_load_lds((const gu32*)gb, (lu32*)&Bl[rbase * 32], 16, 0, 0);
    }
    asm volatile("s_waitcnt vmcnt(0)" ::: "memory");
    __syncthreads();
    bf16x8 af[4], bfr[4];
    #pragma unroll
    for (int mi = 0; mi < 4; mi++) {
      int row = wm * 64 + mi * 16 + (lane & 15);
      af[mi] = *(const bf16x8*)&Al[row * 32 + ((cp ^ ((row >> 1) & 3)) * 8)];
    }
    #pragma unroll
    for (int ni = 0; ni < 4; ni++) {
      int row = wn * 64 + ni * 16 + (lane & 15);
      bfr[ni] = *(const bf16x8*)&Bl[row * 32 + ((cp ^ ((row >> 1) & 3)) * 8)];
    }
    #pragma unroll
    for (int mi = 0; mi < 4; mi++)
      #pragma unroll
      for (int ni = 0; ni < 4; ni++)
        acc[mi][ni] = __builtin_amdgcn_mfma_f32_16x16x32_bf16(af[mi], bfr[ni], acc[mi][ni], 0, 0, 0);
  }
  int col0 = nt * 128 + wn * 64 + (lane & 15);
  int rb = (lane >> 4) * 4;
  #pragma unroll
  for (int mi = 0; mi < 4; mi++) {
    #pragma unroll
    for (int j = 0; j < 4; j++) {
      int o = mt * 128 + wm * 64 + mi * 16 + rb + j;
      float bv = bias[o];
      size_t rowoff = ((size_t)b * 512 + o) * 4480;
      #pragma unroll
      for (int ni = 0; ni < 4; ni++)
        y2[rowoff + col0 + ni * 16] = f2b(acc[mi][ni][j] + bv);
    }
  }
}

// ---------- K8 v13: S2+S3 fused via per-wave LDS scratch (3 barriers, 24576 B LDS) ----------
// S2's output for tile ni is consumed only by the same wave in S3 (same ni deal) ->
// no block barrier, no block-wide At. Atw[wv][16][72] aliases dead Yt.
// Regions: @0 Yt[80][40] (6400B) / Atw 4x[16][72] (9216B) | @9216 T1u[48][104] (9984B) | @19200 T3u[16][168] (5376B)
__launch_bounds__(256, 6)
__global__ void k_updown(const u16* __restrict__ y2,
                         const u16* __restrict__ muv, const u16* __restrict__ muh,
                         const u16* __restrict__ mdv, const u16* __restrict__ mdh,
                         float* __restrict__ out) {
  int g = blockIdx.x, o = blockIdx.y, b = blockIdx.z;
  int t = threadIdx.x, lane = t & 63, wv = t >> 6;
  int l15 = lane & 15, cp = lane >> 4, rb = cp * 4;
  __shared__ __align__(16) char smem[24576];
  u16* Yt  = (u16*)smem;                        // [80][40] (dead after S1)
  u16* Atw = (u16*)(smem + (size_t)wv * 2304);  // per-wave [16][72] (aliases Yt region after S1)
  u16* T1u = (u16*)(smem + 9216);               // [48][104] (live through fused phase)
  u16* T3u = (u16*)(smem + 19200);              // [16][168] (own region)
  const int out_r0 = g * 16;
  const int yrow0 = out_r0 - 4;
  const u16* plane = y2 + ((size_t)b * 512 + o) * 4480;

  // blanket zero all 24576 B (pads + alias-stale cover)
  for (int i = t; i < 1536; i += 256) ((float4*)smem)[i] = make_float4(0.f, 0.f, 0.f, 0.f);
  __syncthreads();
  // stage Y transposed: Yt[j][s] = y[yrow0+s][j]
  for (int idx = t; idx < 26 * 66; idx += 256) {
    int s = idx / 66, j = idx - 66 * s;
    int grow = yrow0 + s;
    u16 v = 0;
    if (grow >= 0 && grow < 66) v = plane[(size_t)grow * 66 + j];
    Yt[j * 40 + s] = v;
  }
  __syncthreads();

  // S1: T1(48x80) = Uv(48x32) x Yt^T   (1 k-step)
  __builtin_amdgcn_s_setprio(1);
  for (int tau = wv; tau < 15; tau += 4) {
    int mi = tau / 5, ni = tau - mi * 5;
    bf16x8 a = *(const bf16x8*)&muv[(mi * 16 + l15) * 32 + cp * 8];
    bf16x8 bfr = *(const bf16x8*)&Yt[(ni * 16 + l15) * 40 + cp * 8];
    f32x4 acc = (f32x4){0.f, 0.f, 0.f, 0.f};
    acc = __builtin_amdgcn_mfma_f32_16x16x32_bf16(a, bfr, acc, 0, 0, 0);
    #pragma unroll
    for (int j = 0; j < 4; j++)
      T1u[(mi * 16 + rb + j) * 104 + ni * 16 + l15] = f2b(acc[j]);
  }
  __builtin_amdgcn_s_setprio(0);
  __syncthreads();

  // Fused S2+S3 per ni (wave-local, no block barrier):
  //   S2: T2 tile (all mi) -> act -> Atw[wv]; wave-local lgkm drain; S3: T3 tile for same ni.
  __builtin_amdgcn_s_setprio(1);
  {
    bf16x8 a0 = *(const bf16x8*)&mdv[l15 * 64 + cp * 8];
    bf16x8 a1 = *(const bf16x8*)&mdv[l15 * 64 + 32 + cp * 8];
    for (int ni = wv; ni < 9; ni += 4) {
      bf16x8 bh[3];
      #pragma unroll
      for (int ks = 0; ks < 3; ks++)
        bh[ks] = *(const bf16x8*)&muh[(ni * 16 + l15) * 96 + ks * 32 + cp * 8];
      #pragma unroll
      for (int mi = 0; mi < 3; mi++) {
        f32x4 acc = (f32x4){0.f, 0.f, 0.f, 0.f};
        #pragma unroll
        for (int ks = 0; ks < 3; ks++) {
          bf16x8 a = *(const bf16x8*)&T1u[(mi * 16 + l15) * 104 + ks * 32 + cp * 8];
          acc = __builtin_amdgcn_mfma_f32_16x16x32_bf16(a, bh[ks], acc, 0, 0, 0);
        }
        u16 pv[4];
        #pragma unroll
        for (int j = 0; j < 4; j++) {
          float x = acc[j];
          x = fmaxf(x, 0.2f * x) * 5.65685424949238f;
          x = fminf(fmaxf(x, -256.f), 256.f);
          pv[j] = f2b(x);
        }
        u32 lo = (u32)pv[0] | ((u32)pv[1] << 16);
        u32 hi = (u32)pv[2] | ((u32)pv[3] << 16);
        *(uint2*)&Atw[l15 * 72 + mi * 16 + rb] = make_uint2(lo, hi);
      }
      asm volatile("s_waitcnt lgkmcnt(0)" ::: "memory");  // wave-local RAW fence
      // S3 for this ni: T3 tile = Dv x Atw^T (2 k-steps)
      f32x4 acc3 = (f32x4){0.f, 0.f, 0.f, 0.f};
      bf16x8 b0 = *(const bf16x8*)&Atw[l15 * 72 + cp * 8];
      acc3 = __builtin_amdgcn_mfma_f32_16x16x32_bf16(a0, b0, acc3, 0, 0, 0);
      bf16x8 b1 = *(const bf16x8*)&Atw[l15 * 72 + 32 + cp * 8];
      acc3 = __builtin_amdgcn_mfma_f32_16x16x32_bf16(a1, b1, acc3, 0, 0, 0);
      #pragma unroll
      for (int j = 0; j < 4; j++)
        T3u[(rb + j) * 168 + ni * 16 + l15] = f2b(acc3[j]);
    }
  }
  __builtin_amdgcn_s_setprio(0);
  __syncthreads();

  // S4: OUT(16x64) = T3(16x160) x Dh^T  (5 k-steps), wave ni = wv
  {
    __builtin_amdgcn_s_setprio(1);
    f32x4 acc = (f32x4){0.f, 0.f, 0.f, 0.f};
    #pragma unroll
    for (int ks = 0; ks < 5; ks++) {
      bf16x8 a = *(const bf16x8*)&T3u[l15 * 168 + ks * 32 + cp * 8];
      bf16x8 bfr = *(const bf16x8*)&mdh[(wv * 16 + l15) * 160 + ks * 32 + cp * 8];
      acc = __builtin_amdgcn_mfma_f32_16x16x32_bf16(a, bfr, acc, 0, 0, 0);
    }
    __builtin_amdgcn_s_setprio(0);
    float* op = out + (((size_t)b * 512 + o) * 64 + out_r0) * 64;
    #pragma unroll
    for (int j = 0; j < 4; j++)
      op[(rb + j) * 64 + wv * 16 + l15] = acc[j];
  }
}

extern "C" void kernel_launch(void* const* d_in, const int* in_sizes, int n_in,
                              void* d_out, int out_size, void* d_ws, size_t ws_size,
                              hipStream_t stream) {
  const float* x     = (const float*)d_in[0];
  const float* w     = (const float*)d_in[1];
  const float* aw    = (const float*)d_in[2];
  const float* ab    = (const float*)d_in[3];
  const float* swgt  = (const float*)d_in[4];
  const float* bias  = (const float*)d_in[5];
  const float* sw0   = (const float*)d_in[6];
  const float* sb0   = (const float*)d_in[7];
  const float* sw1   = (const float*)d_in[8];
  const float* sb1   = (const float*)d_in[9];
  const float* sw2   = (const float*)d_in[10];
  const float* sb2   = (const float*)d_in[11];
  const float* sw3   = (const float*)d_in[12];
  const float* sb3   = (const float*)d_in[13];
  const float* kscl  = (const float*)d_in[14];
  const float* ema   = (const float*)d_in[15];

  float* ws  = (float*)d_ws;
  char*  wsb = (char*)d_ws;
  u16* wbp = (u16*)(wsb + OFFB_WB);
  u16* y2  = (u16*)(wsb + OFFB_Y2);
  u16* y1  = (u16*)(wsb + OFFB_Y1);
  u16* muv = (u16*)(wsb + OFFB_MUV);
  u16* muh = (u16*)(wsb + OFFB_MUH);
  u16* mdv = (u16*)(wsb + OFFB_MDV);
  u16* mdh = (u16*)(wsb + OFFB_MDH);

  k_setup<<<dim3(1), dim3(256), 0, stream>>>(sw0, sb0, sw1, sb1, sw2, sb2, ws);
  k_stkw<<<dim3(72), dim3(256), 0, stream>>>(w, aw, ab, sw3, sb3, kscl, ema, ws);
  k_wb<<<dim3(128, 8), dim3(256), 0, stream>>>(swgt, ws, wbp);
  k_tdw<<<dim3(67, 8, 8), dim3(256), 0, stream>>>(x, ws, y1);
  k_gemm<<<dim3(35, 4, 8), dim3(256), 0, stream>>>(wbp, y1, bias, y2);
  k_updown<<<dim3(4, 512, 8), dim3(256), 0, stream>>>(y2, muv, muh, mdv, mdh, (float*)d_out);
}